// Round 3
// baseline (705.013 us; speedup 1.0000x reference)
//
#include <hip/hip_runtime.h>
#include <math.h>

#define N_NODES 100000
#define HDIM 64
#define INDIM 20
#define OUTDIM 128
#define GB2 1024   // gather2 grid blocks (4 waves each)

__device__ __forceinline__ float4 f4add(float4 a, float4 b) {
    return make_float4(a.x + b.x, a.y + b.y, a.z + b.z, a.w + b.w);
}

// ---------------- degree count (in-degree over dst) --------------------------
__global__ __launch_bounds__(256) void deg_kernel(const int* __restrict__ dst,
                                                  int* __restrict__ deg, int E) {
    int e = blockIdx.x * 256 + threadIdx.x;
    if (e < E) atomicAdd(&deg[dst[e]], 1);
}

__global__ __launch_bounds__(256) void dinv_kernel(const int* __restrict__ deg,
                                                   float* __restrict__ dinv, int n) {
    int i = blockIdx.x * 256 + threadIdx.x;
    if (i < n) dinv[i] = rsqrtf((float)deg[i] + 1.0f);   // +1 = self loop
}

__global__ __launch_bounds__(256) void xs_kernel(const float* __restrict__ x,
                                                 const float* __restrict__ dinv,
                                                 float* __restrict__ xs, int total) {
    int g = blockIdx.x * 256 + threadIdx.x;
    if (g < total) xs[g] = x[g] * dinv[g / INDIM];
}

// ---------------- prefix sum (3-pass) over deg -> rowptr ---------------------
__global__ __launch_bounds__(256) void scan1_kernel(const int* __restrict__ deg,
                                                    int* __restrict__ rowptr,
                                                    int* __restrict__ bsums, int n) {
    __shared__ int s[256];
    int tid = threadIdx.x;
    int i = blockIdx.x * 256 + tid;
    int v = (i < n) ? deg[i] : 0;
    s[tid] = v;
    __syncthreads();
    for (int off = 1; off < 256; off <<= 1) {
        int t = (tid >= off) ? s[tid - off] : 0;
        __syncthreads();
        s[tid] += t;
        __syncthreads();
    }
    if (i < n) rowptr[i] = s[tid] - v;
    if (tid == 255) bsums[blockIdx.x] = s[255];
}

__global__ __launch_bounds__(512) void scan2_kernel(int* __restrict__ bsums, int nb) {
    __shared__ int s[512];
    int tid = threadIdx.x;
    int v = (tid < nb) ? bsums[tid] : 0;
    s[tid] = v;
    __syncthreads();
    for (int off = 1; off < 512; off <<= 1) {
        int t = (tid >= off) ? s[tid - off] : 0;
        __syncthreads();
        s[tid] += t;
        __syncthreads();
    }
    if (tid < nb) bsums[tid] = s[tid] - v;
}

__global__ __launch_bounds__(256) void scan3_kernel(int* __restrict__ rowptr,
                                                    const int* __restrict__ bsums,
                                                    int n, int E) {
    int i = blockIdx.x * 256 + threadIdx.x;
    if (i < n) rowptr[i] += bsums[blockIdx.x];
    if (i == 0) rowptr[n] = E;
}

// ---------------- CSR fill: bucket src ids by dst ----------------------------
__global__ __launch_bounds__(256) void fill_kernel(const int* __restrict__ src,
                                                   const int* __restrict__ dst,
                                                   const int* __restrict__ rowptr,
                                                   int* __restrict__ cursor,
                                                   int* __restrict__ csr, int E) {
    int e = blockIdx.x * 256 + threadIdx.x;
    if (e < E) {
        int d = dst[e];
        int pos = rowptr[d] + atomicAdd(&cursor[d], 1);
        csr[pos] = src[e];
    }
}

// ------- gather layer-1 in INPUT space ---------------------------------------
// aggx[i] = dinv[i] * (xs[i] + sum_nbr xs[nbr]),  xs rows = 20 floats = 5 float4.
// 12 lane-groups of 5: group g handles neighbor k+g, lane chunk = lane%5.
__global__ __launch_bounds__(256) void gather1_kernel(const int* __restrict__ rowptr,
                                                      const int* __restrict__ csr,
                                                      const float* __restrict__ xs,
                                                      const float* __restrict__ dinv,
                                                      float* __restrict__ aggx, int n) {
    int tid = threadIdx.x;
    int w = (blockIdx.x * 256 + tid) >> 6;
    int lane = tid & 63;
    if (w >= n) return;
    int rg = lane / 5;          // 0..12 (12 = lanes 60-63, inactive)
    int ch = lane - rg * 5;     // 0..4
    bool act = lane < 60;
    float4 acc = make_float4(0.f, 0.f, 0.f, 0.f);
    if (rg == 0)   // self loop: lanes 0-4 load own row
        acc = *reinterpret_cast<const float4*>(&xs[(size_t)w * INDIM + ch * 4]);
    int beg = rowptr[w], end = rowptr[w + 1];
    for (int base = beg; base < end; base += 64) {
        int cnt = min(64, end - base);
        int myi = (lane < cnt) ? csr[base + lane] : 0;
        int k = 0;
        for (; k + 12 <= cnt; k += 12) {          // all 12 groups full
            int nb = __shfl(myi, k + rg);
            if (act)
                acc = f4add(acc, *reinterpret_cast<const float4*>(
                                     &xs[(size_t)nb * INDIM + ch * 4]));
        }
        if (k < cnt) {                            // tail, predicated
            int kk = k + rg;
            if (act && kk < cnt) {
                int nb = __shfl(myi, kk);
                acc = f4add(acc, *reinterpret_cast<const float4*>(
                                     &xs[(size_t)nb * INDIM + ch * 4]));
            }
        }
    }
    // reduce 12 groups -> group 0 (lanes 0-4). All shfl sources valid for the
    // lanes we consume (see derivation): 12->6 (down30), 6->3 (down15),
    // 3->1 (down5 + down10 from the same value).
    #define F4DOWN(v, d) make_float4(__shfl_down((v).x, d), __shfl_down((v).y, d), \
                                     __shfl_down((v).z, d), __shfl_down((v).w, d))
    acc = f4add(acc, F4DOWN(acc, 30));
    acc = f4add(acc, F4DOWN(acc, 15));
    float4 a5 = F4DOWN(acc, 5);
    float4 a10 = F4DOWN(acc, 10);
    acc = f4add(f4add(acc, a5), a10);
    if (lane < 5) {
        float dw = dinv[w];
        float4 o = make_float4(acc.x * dw, acc.y * dw, acc.z * dw, acc.w * dw);
        *reinterpret_cast<float4*>(&aggx[(size_t)w * INDIM + lane * 4]) = o;
    }
}

// ------- fused mm: v1 = relu(aggx@W1+b1); hs2 = (v1@W2)*dinv -----------------
__global__ __launch_bounds__(256) void mm12_kernel(const float* __restrict__ aggx,
                                                   const float* __restrict__ W1,
                                                   const float* __restrict__ b1,
                                                   const float* __restrict__ W2,
                                                   const float* __restrict__ dinv,
                                                   float* __restrict__ hs2, int n) {
    __shared__ float W1s[INDIM * HDIM];
    __shared__ float W2s[HDIM * HDIM];
    __shared__ float ax[4][INDIM];
    __shared__ float v1s[4][HDIM];
    int tid = threadIdx.x;
    for (int idx = tid; idx < INDIM * HDIM; idx += 256) W1s[idx] = W1[idx];
    for (int idx = tid; idx < HDIM * HDIM; idx += 256) W2s[idx] = W2[idx];
    int sub = tid >> 6;
    int f = tid & 63;
    int i00 = blockIdx.x * 16;
    for (int it = 0; it < 4; ++it) {
        int i0 = i00 + it * 4;
        __syncthreads();
        for (int idx = tid; idx < 4 * INDIM; idx += 256) {
            int node = i0 + idx / INDIM;
            ax[idx / INDIM][idx % INDIM] =
                (node < n) ? aggx[(size_t)node * INDIM + idx % INDIM] : 0.0f;
        }
        __syncthreads();
        float acc = b1[f];
        #pragma unroll
        for (int k = 0; k < INDIM; ++k) acc += ax[sub][k] * W1s[k * HDIM + f];
        v1s[sub][f] = fmaxf(acc, 0.0f);
        __syncthreads();
        int i = i0 + sub;
        if (i < n) {
            float acc2 = 0.0f;
            #pragma unroll
            for (int k = 0; k < HDIM; ++k) acc2 += v1s[sub][k] * W2s[k * HDIM + f];
            hs2[(size_t)i * HDIM + f] = acc2 * dinv[i];
        }
    }
}

// ------- gather layer-2 + fused mean partial ---------------------------------
// 4 lane-groups of 16: group g handles neighbor k+g, lane chunk = lane&15
// (float4 over 64 features). Grid-stride over nodes; relu'd rows accumulate
// into per-wave registers -> LDS block partial -> gpart[block][64].
__global__ __launch_bounds__(256) void gather2_kernel(const int* __restrict__ rowptr,
                                                      const int* __restrict__ csr,
                                                      const float* __restrict__ hs2,
                                                      const float* __restrict__ dinv,
                                                      const float* __restrict__ b2,
                                                      float* __restrict__ gpart, int n) {
    __shared__ float4 shp[4][16];
    int tid = threadIdx.x;
    int wv = tid >> 6;
    int lane = tid & 63;
    int rg = lane >> 4;        // 0..3
    int ch = lane & 15;        // 0..15
    float4 b2c = *reinterpret_cast<const float4*>(&b2[ch * 4]);
    float4 vsum = make_float4(0.f, 0.f, 0.f, 0.f);
    int gw = blockIdx.x * 4 + wv;
    for (int w = gw; w < n; w += GB2 * 4) {
        float4 acc = make_float4(0.f, 0.f, 0.f, 0.f);
        float4 acc2 = make_float4(0.f, 0.f, 0.f, 0.f);
        if (rg == 0)   // self loop
            acc = *reinterpret_cast<const float4*>(&hs2[(size_t)w * HDIM + ch * 4]);
        int beg = rowptr[w], end = rowptr[w + 1];
        for (int base = beg; base < end; base += 64) {
            int cnt = min(64, end - base);
            int myi = (lane < cnt) ? csr[base + lane] : 0;
            int k = 0;
            for (; k + 8 <= cnt; k += 8) {       // 2x unroll: 2 KB in flight
                int nb0 = __shfl(myi, k + rg);
                int nb1 = __shfl(myi, k + 4 + rg);
                float4 v0 = *reinterpret_cast<const float4*>(
                    &hs2[(size_t)nb0 * HDIM + ch * 4]);
                float4 v1 = *reinterpret_cast<const float4*>(
                    &hs2[(size_t)nb1 * HDIM + ch * 4]);
                acc = f4add(acc, v0);
                acc2 = f4add(acc2, v1);
            }
            for (; k < cnt; k += 4) {            // tail, predicated
                int kk = k + rg;
                if (kk < cnt) {
                    int nb = __shfl(myi, kk);
                    acc = f4add(acc, *reinterpret_cast<const float4*>(
                                         &hs2[(size_t)nb * HDIM + ch * 4]));
                }
            }
        }
        acc = f4add(acc, acc2);
        // butterfly across the 4 groups: every lane ends with chunk total
        acc.x += __shfl_xor(acc.x, 16); acc.y += __shfl_xor(acc.y, 16);
        acc.z += __shfl_xor(acc.z, 16); acc.w += __shfl_xor(acc.w, 16);
        acc.x += __shfl_xor(acc.x, 32); acc.y += __shfl_xor(acc.y, 32);
        acc.z += __shfl_xor(acc.z, 32); acc.w += __shfl_xor(acc.w, 32);
        float dw = dinv[w];
        vsum.x += fmaxf(acc.x * dw + b2c.x, 0.0f);
        vsum.y += fmaxf(acc.y * dw + b2c.y, 0.0f);
        vsum.z += fmaxf(acc.z * dw + b2c.z, 0.0f);
        vsum.w += fmaxf(acc.w * dw + b2c.w, 0.0f);
    }
    if (rg == 0) shp[wv][ch] = vsum;
    __syncthreads();
    if (tid < 64) {
        const float* sp = (const float*)shp;
        float s = sp[tid] + sp[64 + tid] + sp[128 + tid] + sp[192 + tid];
        gpart[(size_t)blockIdx.x * HDIM + tid] = s;
    }
}

// ---------------- partial reduce + tiny MLP head ------------------------------
__global__ __launch_bounds__(256) void head_kernel(const float* __restrict__ gpart,
                                                   const float* __restrict__ fcW1,
                                                   const float* __restrict__ fcb1,
                                                   const float* __restrict__ fcW2,
                                                   const float* __restrict__ fcb2,
                                                   float* __restrict__ out, int n) {
    __shared__ float lds[256];
    __shared__ float g[HDIM];
    __shared__ float t1[HDIM];
    int tid = threadIdx.x;
    int q = tid >> 6;
    int f = tid & 63;
    float s = 0.0f;
    for (int b = q; b < GB2; b += 4) s += gpart[(size_t)b * HDIM + f];
    lds[tid] = s;
    __syncthreads();
    if (tid < 64)
        g[tid] = (lds[tid] + lds[64 + tid] + lds[128 + tid] + lds[192 + tid]) *
                 (1.0f / (float)n);
    __syncthreads();
    if (tid < 64) {
        float acc = fcb1[tid];
        #pragma unroll
        for (int k = 0; k < HDIM; ++k) acc += g[k] * fcW1[k * HDIM + tid];
        t1[tid] = fmaxf(acc, 0.0f);
    }
    __syncthreads();
    if (tid < OUTDIM) {
        float acc = fcb2[tid];
        #pragma unroll
        for (int j = 0; j < HDIM; ++j) acc += t1[j] * fcW2[j * OUTDIM + tid];
        out[tid] = 1.0f / (1.0f + expf(-acc));
    }
}

extern "C" void kernel_launch(void* const* d_in, const int* in_sizes, int n_in,
                              void* d_out, int out_size, void* d_ws, size_t ws_size,
                              hipStream_t stream) {
    const float* x    = (const float*)d_in[0];
    const int*   ei   = (const int*)d_in[1];
    const float* W1   = (const float*)d_in[2];
    const float* b1   = (const float*)d_in[3];
    const float* W2   = (const float*)d_in[4];
    const float* b2   = (const float*)d_in[5];
    const float* fcW1 = (const float*)d_in[6];
    const float* fcb1 = (const float*)d_in[7];
    const float* fcW2 = (const float*)d_in[8];
    const float* fcb2 = (const float*)d_in[9];
    float* out = (float*)d_out;

    const int n = N_NODES;
    const int E = in_sizes[1] / 2;
    const int* src = ei;
    const int* dst = ei + E;

    char* ws = (char*)d_ws;
    size_t off = 0;
    auto alloc = [&](size_t bytes) -> void* {
        void* p = ws + off;
        off = (off + bytes + 255) & ~(size_t)255;
        return p;
    };
    int*   deg    = (int*)  alloc((size_t)n * 4);
    float* dinv   = (float*)alloc((size_t)n * 4);
    int*   rowptr = (int*)  alloc((size_t)(n + 1) * 4);
    int*   cursor = (int*)  alloc((size_t)n * 4);
    int*   bsums  = (int*)  alloc(512 * 4);
    int*   csr    = (int*)  alloc((size_t)E * 4);
    float* hs2    = (float*)alloc((size_t)n * HDIM * 4);
    float* xs     = (float*)alloc((size_t)n * INDIM * 4);
    float* aggx   = (float*)alloc((size_t)n * INDIM * 4);
    float* gpart  = (float*)alloc((size_t)GB2 * HDIM * 4);
    (void)ws_size;

    hipMemsetAsync(deg, 0, (size_t)n * 4, stream);
    hipMemsetAsync(cursor, 0, (size_t)n * 4, stream);

    deg_kernel<<<(E + 255) / 256, 256, 0, stream>>>(dst, deg, E);
    dinv_kernel<<<(n + 255) / 256, 256, 0, stream>>>(deg, dinv, n);
    xs_kernel<<<(n * INDIM + 255) / 256, 256, 0, stream>>>(x, dinv, xs, n * INDIM);

    int nb = (n + 255) / 256;
    scan1_kernel<<<nb, 256, 0, stream>>>(deg, rowptr, bsums, n);
    scan2_kernel<<<1, 512, 0, stream>>>(bsums, nb);
    scan3_kernel<<<nb, 256, 0, stream>>>(rowptr, bsums, n, E);
    fill_kernel<<<(E + 255) / 256, 256, 0, stream>>>(src, dst, rowptr, cursor, csr, E);

    int g1blocks = (n * 64 + 255) / 256;
    gather1_kernel<<<g1blocks, 256, 0, stream>>>(rowptr, csr, xs, dinv, aggx, n);
    mm12_kernel<<<(n + 15) / 16, 256, 0, stream>>>(aggx, W1, b1, W2, dinv, hs2, n);
    gather2_kernel<<<GB2, 256, 0, stream>>>(rowptr, csr, hs2, dinv, b2, gpart, n);

    head_kernel<<<1, 256, 0, stream>>>(gpart, fcW1, fcb1, fcW2, fcb2, out, n);
}

// Round 5
// 544.743 us; speedup vs baseline: 1.2942x; 1.2942x over previous
//
#include <hip/hip_runtime.h>
#include <math.h>

#define N_NODES 100000
#define HDIM 64
#define INDIM 20
#define OUTDIM 128
#define GB2 2048    // gather2 grid blocks (4 waves each)
#define BSHIFT 9    // 512 nodes per bucket
#define NB 196      // ceil(100000 / 512)
#define CHUNK 3072  // edges per partition block
#define CPAD 16     // ints per padded counter (one 64B line)

__device__ __forceinline__ float4 f4add(float4 a, float4 b) {
    return make_float4(a.x + b.x, a.y + b.y, a.z + b.z, a.w + b.w);
}

// ---- pass 1: coarse histogram of dst buckets (LDS-privatized) ---------------
__global__ __launch_bounds__(256) void hist_kernel(const int* __restrict__ dst,
                                                   int* __restrict__ bucketCount, int E) {
    __shared__ int h[NB];
    int tid = threadIdx.x;
    for (int b = tid; b < NB; b += 256) h[b] = 0;
    __syncthreads();
    for (int e = blockIdx.x * 256 + tid; e < E; e += gridDim.x * 256)
        atomicAdd(&h[dst[e] >> BSHIFT], 1);
    __syncthreads();
    for (int b = tid; b < NB; b += 256)
        if (h[b]) atomicAdd(&bucketCount[b * CPAD], h[b]);
}

// ---- pass 2: scan bucket counts -> bases + working cursors ------------------
__global__ __launch_bounds__(256) void bscan_kernel(const int* __restrict__ bucketCount,
                                                    int* __restrict__ bucketBase,
                                                    int* __restrict__ bucketCursor,
                                                    int* __restrict__ rowptr, int E) {
    __shared__ int s[256];
    int tid = threadIdx.x;
    int v = (tid < NB) ? bucketCount[tid * CPAD] : 0;
    s[tid] = v;
    __syncthreads();
    for (int off = 1; off < 256; off <<= 1) {
        int t = (tid >= off) ? s[tid - off] : 0;
        __syncthreads();
        s[tid] += t;
        __syncthreads();
    }
    if (tid < NB) {
        int base = s[tid] - v;
        bucketBase[tid] = base;
        bucketCursor[tid * CPAD] = base;
    }
    if (tid == 0) { bucketBase[NB] = E; rowptr[N_NODES] = E; }
}

// ---- pass 3: partition edges into bucket-grouped packed ebuf ----------------
// packed = (src << 9) | (dst & 511); src < 2^17 so fits 26 bits.
__global__ __launch_bounds__(256) void part_kernel(const int* __restrict__ src,
                                                   const int* __restrict__ dst,
                                                   int* __restrict__ bucketCursor,
                                                   int* __restrict__ ebuf, int E) {
    __shared__ int cnt[NB];
    __shared__ int base[NB];
    int tid = threadIdx.x;
    int e0 = blockIdx.x * CHUNK;
    int e1 = min(E, e0 + CHUNK);
    for (int b = tid; b < NB; b += 256) cnt[b] = 0;
    __syncthreads();
    for (int e = e0 + tid; e < e1; e += 256)
        atomicAdd(&cnt[dst[e] >> BSHIFT], 1);
    __syncthreads();
    for (int b = tid; b < NB; b += 256) {
        int c = cnt[b];
        base[b] = c ? atomicAdd(&bucketCursor[b * CPAD], c) : 0;
        cnt[b] = 0;
    }
    __syncthreads();
    for (int e = e0 + tid; e < e1; e += 256) {
        int d = dst[e];
        int b = d >> BSHIFT;
        int off = atomicAdd(&cnt[b], 1);
        ebuf[base[b] + off] = (src[e] << BSHIFT) | (d & ((1 << BSHIFT) - 1));
    }
}

// ---- pass 4: per-bucket CSR build + rowptr + dinv (all LDS atomics) ---------
__global__ __launch_bounds__(256) void build_kernel(const int* __restrict__ ebuf,
                                                    const int* __restrict__ bucketBase,
                                                    int* __restrict__ rowptr,
                                                    int* __restrict__ csr,
                                                    float* __restrict__ dinv, int n) {
    __shared__ int hist[512];
    __shared__ int cur[512];
    __shared__ int ps[256];
    int tid = threadIdx.x;
    int b = blockIdx.x;
    int nodeBase = b << BSHIFT;
    int ebeg = bucketBase[b], eend = bucketBase[b + 1];
    hist[tid] = 0; hist[tid + 256] = 0;
    cur[tid] = 0;  cur[tid + 256] = 0;
    __syncthreads();
    for (int e = ebeg + tid; e < eend; e += 256)
        atomicAdd(&hist[ebuf[e] & 511], 1);
    __syncthreads();
    int s0 = hist[2 * tid], s1 = hist[2 * tid + 1];
    ps[tid] = s0 + s1;
    __syncthreads();
    for (int off = 1; off < 256; off <<= 1) {
        int t = (tid >= off) ? ps[tid - off] : 0;
        __syncthreads();
        ps[tid] += t;
        __syncthreads();
    }
    int ex = ps[tid] - (s0 + s1);   // exclusive prefix for node 2*tid
    int i0 = 2 * tid, i1 = 2 * tid + 1;
    if (nodeBase + i0 < n) {
        rowptr[nodeBase + i0] = ebeg + ex;
        dinv[nodeBase + i0] = rsqrtf((float)s0 + 1.0f);
    }
    if (nodeBase + i1 < n) {
        rowptr[nodeBase + i1] = ebeg + ex + s0;
        dinv[nodeBase + i1] = rsqrtf((float)s1 + 1.0f);
    }
    hist[i0] = ex;
    hist[i1] = ex + s0;
    __syncthreads();
    for (int e = ebeg + tid; e < eend; e += 256) {
        int p = ebuf[e];
        int d = p & 511;
        int pos = hist[d] + atomicAdd(&cur[d], 1);
        csr[ebeg + pos] = p >> BSHIFT;   // p >= 0, logical shift
    }
}

// ---- xs = x * dinv ----------------------------------------------------------
__global__ __launch_bounds__(256) void xs_kernel(const float* __restrict__ x,
                                                 const float* __restrict__ dinv,
                                                 float* __restrict__ xs, int total) {
    int g = blockIdx.x * 256 + threadIdx.x;
    if (g < total) xs[g] = x[g] * dinv[g / INDIM];
}

// ------- gather layer-1 in INPUT space ---------------------------------------
// aggx[i] = dinv[i] * (xs[i] + sum_nbr xs[nbr]); 12 lane-groups of 5 lanes,
// each group covers one neighbor row (5 float4 chunks of 20 floats).
__global__ __launch_bounds__(256) void gather1_kernel(const int* __restrict__ rowptr,
                                                      const int* __restrict__ csr,
                                                      const float* __restrict__ xs,
                                                      const float* __restrict__ dinv,
                                                      float* __restrict__ aggx, int n) {
    int tid = threadIdx.x;
    int w = (blockIdx.x * 256 + tid) >> 6;
    int lane = tid & 63;
    if (w >= n) return;
    int rg = lane / 5;
    int ch = lane - rg * 5;
    bool act = lane < 60;
    float4 acc = make_float4(0.f, 0.f, 0.f, 0.f);
    if (rg == 0)
        acc = *reinterpret_cast<const float4*>(&xs[(size_t)w * INDIM + ch * 4]);
    int beg = rowptr[w], end = rowptr[w + 1];
    for (int base = beg; base < end; base += 64) {
        int cnt = min(64, end - base);
        int myi = (lane < cnt) ? csr[base + lane] : 0;
        int k = 0;
        for (; k + 12 <= cnt; k += 12) {
            int nb = __shfl(myi, k + rg);
            if (act)
                acc = f4add(acc, *reinterpret_cast<const float4*>(
                                     &xs[(size_t)nb * INDIM + ch * 4]));
        }
        if (k < cnt) {
            int kk = k + rg;
            if (act && kk < cnt) {
                int nb = __shfl(myi, kk);
                acc = f4add(acc, *reinterpret_cast<const float4*>(
                                     &xs[(size_t)nb * INDIM + ch * 4]));
            }
        }
    }
    #define F4DOWN(v, d) make_float4(__shfl_down((v).x, d), __shfl_down((v).y, d), \
                                     __shfl_down((v).z, d), __shfl_down((v).w, d))
    acc = f4add(acc, F4DOWN(acc, 30));
    acc = f4add(acc, F4DOWN(acc, 15));
    float4 a5 = F4DOWN(acc, 5);
    float4 a10 = F4DOWN(acc, 10);
    acc = f4add(f4add(acc, a5), a10);
    if (lane < 5) {
        float dw = dinv[w];
        float4 o = make_float4(acc.x * dw, acc.y * dw, acc.z * dw, acc.w * dw);
        *reinterpret_cast<float4*>(&aggx[(size_t)w * INDIM + lane * 4]) = o;
    }
}

// ------- fused mm: v1 = relu(aggx@W1+b1); hs2 = (v1@W2)*dinv -----------------
__global__ __launch_bounds__(256) void mm12_kernel(const float* __restrict__ aggx,
                                                   const float* __restrict__ W1,
                                                   const float* __restrict__ b1,
                                                   const float* __restrict__ W2,
                                                   const float* __restrict__ dinv,
                                                   float* __restrict__ hs2, int n) {
    __shared__ float W1s[INDIM * HDIM];
    __shared__ float W2s[HDIM * HDIM];
    __shared__ float ax[4][INDIM];
    __shared__ float v1s[4][HDIM];
    int tid = threadIdx.x;
    for (int idx = tid; idx < INDIM * HDIM; idx += 256) W1s[idx] = W1[idx];
    for (int idx = tid; idx < HDIM * HDIM; idx += 256) W2s[idx] = W2[idx];
    int sub = tid >> 6;
    int f = tid & 63;
    int i00 = blockIdx.x * 16;
    for (int it = 0; it < 4; ++it) {
        int i0 = i00 + it * 4;
        __syncthreads();
        for (int idx = tid; idx < 4 * INDIM; idx += 256) {
            int node = i0 + idx / INDIM;
            ax[idx / INDIM][idx % INDIM] =
                (node < n) ? aggx[(size_t)node * INDIM + idx % INDIM] : 0.0f;
        }
        __syncthreads();
        float acc = b1[f];
        #pragma unroll
        for (int k = 0; k < INDIM; ++k) acc += ax[sub][k] * W1s[k * HDIM + f];
        v1s[sub][f] = fmaxf(acc, 0.0f);
        __syncthreads();
        int i = i0 + sub;
        if (i < n) {
            float acc2 = 0.0f;
            #pragma unroll
            for (int k = 0; k < HDIM; ++k) acc2 += v1s[sub][k] * W2s[k * HDIM + f];
            hs2[(size_t)i * HDIM + f] = acc2 * dinv[i];
        }
    }
}

// ------- gather layer-2 + fused mean partial ---------------------------------
// 4 lane-groups of 16; 4-deep unroll = 16 neighbor rows (4 KB) in flight/wave.
__global__ __launch_bounds__(256) void gather2_kernel(const int* __restrict__ rowptr,
                                                      const int* __restrict__ csr,
                                                      const float* __restrict__ hs2,
                                                      const float* __restrict__ dinv,
                                                      const float* __restrict__ b2,
                                                      float* __restrict__ gpart, int n) {
    __shared__ float4 shp[4][16];
    int tid = threadIdx.x;
    int wv = tid >> 6;
    int lane = tid & 63;
    int rg = lane >> 4;
    int ch = lane & 15;
    float4 b2c = *reinterpret_cast<const float4*>(&b2[ch * 4]);
    float4 vsum = make_float4(0.f, 0.f, 0.f, 0.f);
    int gw = blockIdx.x * 4 + wv;
    for (int w = gw; w < n; w += GB2 * 4) {
        float4 acc0 = make_float4(0.f, 0.f, 0.f, 0.f);
        float4 acc1 = make_float4(0.f, 0.f, 0.f, 0.f);
        float4 acc2 = make_float4(0.f, 0.f, 0.f, 0.f);
        float4 acc3 = make_float4(0.f, 0.f, 0.f, 0.f);
        if (rg == 0)
            acc0 = *reinterpret_cast<const float4*>(&hs2[(size_t)w * HDIM + ch * 4]);
        int beg = rowptr[w], end = rowptr[w + 1];
        for (int base = beg; base < end; base += 64) {
            int cnt = min(64, end - base);
            int myi = (lane < cnt) ? csr[base + lane] : 0;
            int k = 0;
            for (; k + 16 <= cnt; k += 16) {
                int nb0 = __shfl(myi, k + rg);
                int nb1 = __shfl(myi, k + 4 + rg);
                int nb2 = __shfl(myi, k + 8 + rg);
                int nb3 = __shfl(myi, k + 12 + rg);
                float4 v0 = *reinterpret_cast<const float4*>(&hs2[(size_t)nb0 * HDIM + ch * 4]);
                float4 v1 = *reinterpret_cast<const float4*>(&hs2[(size_t)nb1 * HDIM + ch * 4]);
                float4 v2 = *reinterpret_cast<const float4*>(&hs2[(size_t)nb2 * HDIM + ch * 4]);
                float4 v3 = *reinterpret_cast<const float4*>(&hs2[(size_t)nb3 * HDIM + ch * 4]);
                acc0 = f4add(acc0, v0);
                acc1 = f4add(acc1, v1);
                acc2 = f4add(acc2, v2);
                acc3 = f4add(acc3, v3);
            }
            for (; k + 8 <= cnt; k += 8) {
                int nb0 = __shfl(myi, k + rg);
                int nb1 = __shfl(myi, k + 4 + rg);
                float4 v0 = *reinterpret_cast<const float4*>(&hs2[(size_t)nb0 * HDIM + ch * 4]);
                float4 v1 = *reinterpret_cast<const float4*>(&hs2[(size_t)nb1 * HDIM + ch * 4]);
                acc0 = f4add(acc0, v0);
                acc1 = f4add(acc1, v1);
            }
            for (; k < cnt; k += 4) {
                int kk = k + rg;
                if (kk < cnt) {
                    int nb = __shfl(myi, kk);
                    acc0 = f4add(acc0, *reinterpret_cast<const float4*>(
                                           &hs2[(size_t)nb * HDIM + ch * 4]));
                }
            }
        }
        float4 acc = f4add(f4add(acc0, acc1), f4add(acc2, acc3));
        acc.x += __shfl_xor(acc.x, 16); acc.y += __shfl_xor(acc.y, 16);
        acc.z += __shfl_xor(acc.z, 16); acc.w += __shfl_xor(acc.w, 16);
        acc.x += __shfl_xor(acc.x, 32); acc.y += __shfl_xor(acc.y, 32);
        acc.z += __shfl_xor(acc.z, 32); acc.w += __shfl_xor(acc.w, 32);
        float dw = dinv[w];
        vsum.x += fmaxf(acc.x * dw + b2c.x, 0.0f);
        vsum.y += fmaxf(acc.y * dw + b2c.y, 0.0f);
        vsum.z += fmaxf(acc.z * dw + b2c.z, 0.0f);
        vsum.w += fmaxf(acc.w * dw + b2c.w, 0.0f);
    }
    if (rg == 0) shp[wv][ch] = vsum;
    __syncthreads();
    if (tid < 64) {
        const float* sp = (const float*)shp;
        float s = sp[tid] + sp[64 + tid] + sp[128 + tid] + sp[192 + tid];
        gpart[(size_t)blockIdx.x * HDIM + tid] = s;
    }
}

// ---------------- partial reduce + tiny MLP head ------------------------------
__global__ __launch_bounds__(256) void head_kernel(const float* __restrict__ gpart,
                                                   const float* __restrict__ fcW1,
                                                   const float* __restrict__ fcb1,
                                                   const float* __restrict__ fcW2,
                                                   const float* __restrict__ fcb2,
                                                   float* __restrict__ out, int n) {
    __shared__ float lds[256];
    __shared__ float g[HDIM];
    __shared__ float t1[HDIM];
    int tid = threadIdx.x;
    int q = tid >> 6;
    int f = tid & 63;
    float s = 0.0f;
    for (int b = q; b < GB2; b += 4) s += gpart[(size_t)b * HDIM + f];
    lds[tid] = s;
    __syncthreads();
    if (tid < 64)
        g[tid] = (lds[tid] + lds[64 + tid] + lds[128 + tid] + lds[192 + tid]) *
                 (1.0f / (float)n);
    __syncthreads();
    if (tid < 64) {
        float acc = fcb1[tid];
        #pragma unroll
        for (int k = 0; k < HDIM; ++k) acc += g[k] * fcW1[k * HDIM + tid];
        t1[tid] = fmaxf(acc, 0.0f);
    }
    __syncthreads();
    if (tid < OUTDIM) {
        float acc = fcb2[tid];
        #pragma unroll
        for (int j = 0; j < HDIM; ++j) acc += t1[j] * fcW2[j * OUTDIM + tid];
        out[tid] = 1.0f / (1.0f + expf(-acc));
    }
}

extern "C" void kernel_launch(void* const* d_in, const int* in_sizes, int n_in,
                              void* d_out, int out_size, void* d_ws, size_t ws_size,
                              hipStream_t stream) {
    const float* x    = (const float*)d_in[0];
    const int*   ei   = (const int*)d_in[1];
    const float* W1   = (const float*)d_in[2];
    const float* b1   = (const float*)d_in[3];
    const float* W2   = (const float*)d_in[4];
    const float* b2   = (const float*)d_in[5];
    const float* fcW1 = (const float*)d_in[6];
    const float* fcb1 = (const float*)d_in[7];
    const float* fcW2 = (const float*)d_in[8];
    const float* fcb2 = (const float*)d_in[9];
    float* out = (float*)d_out;

    const int n = N_NODES;
    const int E = in_sizes[1] / 2;
    const int* src = ei;
    const int* dst = ei + E;

    char* ws = (char*)d_ws;
    size_t off = 0;
    auto alloc = [&](size_t bytes) -> void* {
        void* p = ws + off;
        off = (off + bytes + 255) & ~(size_t)255;
        return p;
    };
    float* dinv    = (float*)alloc((size_t)n * 4);
    int*   rowptr  = (int*)  alloc((size_t)(n + 1) * 4);
    int*   bCount  = (int*)  alloc((size_t)NB * CPAD * 4);
    int*   bBase   = (int*)  alloc((NB + 1) * 4);
    int*   bCursor = (int*)  alloc((size_t)NB * CPAD * 4);
    int*   csr     = (int*)  alloc((size_t)E * 4);
    int*   ebuf    = (int*)  alloc((size_t)E * 4);
    float* hs2     = (float*)alloc((size_t)n * HDIM * 4);
    float* xs      = (float*)alloc((size_t)n * INDIM * 4);
    float* aggx    = (float*)alloc((size_t)n * INDIM * 4);
    float* gpart   = (float*)alloc((size_t)GB2 * HDIM * 4);
    (void)ws_size;

    hipMemsetAsync(bCount, 0, (size_t)NB * CPAD * 4, stream);

    // CSR build: hist -> scan -> partition -> per-bucket build (+rowptr +dinv)
    hist_kernel<<<512, 256, 0, stream>>>(dst, bCount, E);
    bscan_kernel<<<1, 256, 0, stream>>>(bCount, bBase, bCursor, rowptr, E);
    part_kernel<<<(E + CHUNK - 1) / CHUNK, 256, 0, stream>>>(src, dst, bCursor, ebuf, E);
    build_kernel<<<NB, 256, 0, stream>>>(ebuf, bBase, rowptr, csr, dinv, n);

    xs_kernel<<<(n * INDIM + 255) / 256, 256, 0, stream>>>(x, dinv, xs, n * INDIM);

    int g1blocks = (n * 64 + 255) / 256;
    gather1_kernel<<<g1blocks, 256, 0, stream>>>(rowptr, csr, xs, dinv, aggx, n);
    mm12_kernel<<<(n + 15) / 16, 256, 0, stream>>>(aggx, W1, b1, W2, dinv, hs2, n);
    gather2_kernel<<<GB2, 256, 0, stream>>>(rowptr, csr, hs2, dinv, b2, gpart, n);

    head_kernel<<<1, 256, 0, stream>>>(gpart, fcW1, fcb1, fcW2, fcb2, out, n);
}

// Round 6
// 431.411 us; speedup vs baseline: 1.6342x; 1.2627x over previous
//
#include <hip/hip_runtime.h>
#include <math.h>

#define N_NODES 100000
#define HDIM 64
#define INDIM 20
#define OUTDIM 128
#define GB2 2048    // gather2 grid blocks (4 waves each)
#define GB2R 64     // stage-2 reduction blocks
#define BSHIFT 9    // 512 nodes per bucket
#define NB 196      // ceil(100000 / 512)
#define CHUNK 3072  // edges per partition block
#define CPAD 16     // ints per padded counter (one 64B line)

__device__ __forceinline__ float4 f4add(float4 a, float4 b) {
    return make_float4(a.x + b.x, a.y + b.y, a.z + b.z, a.w + b.w);
}

// ---- pass 1: coarse histogram of dst buckets (LDS-privatized) ---------------
__global__ __launch_bounds__(256) void hist_kernel(const int* __restrict__ dst,
                                                   int* __restrict__ bucketCount, int E) {
    __shared__ int h[NB];
    int tid = threadIdx.x;
    for (int b = tid; b < NB; b += 256) h[b] = 0;
    __syncthreads();
    for (int e = blockIdx.x * 256 + tid; e < E; e += gridDim.x * 256)
        atomicAdd(&h[dst[e] >> BSHIFT], 1);
    __syncthreads();
    for (int b = tid; b < NB; b += 256)
        if (h[b]) atomicAdd(&bucketCount[b * CPAD], h[b]);
}

// ---- pass 2: scan bucket counts -> bases + working cursors ------------------
__global__ __launch_bounds__(256) void bscan_kernel(const int* __restrict__ bucketCount,
                                                    int* __restrict__ bucketBase,
                                                    int* __restrict__ bucketCursor,
                                                    int* __restrict__ rowptr, int E) {
    __shared__ int s[256];
    int tid = threadIdx.x;
    int v = (tid < NB) ? bucketCount[tid * CPAD] : 0;
    s[tid] = v;
    __syncthreads();
    for (int off = 1; off < 256; off <<= 1) {
        int t = (tid >= off) ? s[tid - off] : 0;
        __syncthreads();
        s[tid] += t;
        __syncthreads();
    }
    if (tid < NB) {
        int base = s[tid] - v;
        bucketBase[tid] = base;
        bucketCursor[tid * CPAD] = base;
    }
    if (tid == 0) { bucketBase[NB] = E; rowptr[N_NODES] = E; }
}

// ---- pass 3: partition edges into bucket-grouped packed ebuf ----------------
// packed = (src << 9) | (dst & 511); src < 2^17 so fits 26 bits.
__global__ __launch_bounds__(256) void part_kernel(const int* __restrict__ src,
                                                   const int* __restrict__ dst,
                                                   int* __restrict__ bucketCursor,
                                                   int* __restrict__ ebuf, int E) {
    __shared__ int cnt[NB];
    __shared__ int base[NB];
    int tid = threadIdx.x;
    int e0 = blockIdx.x * CHUNK;
    int e1 = min(E, e0 + CHUNK);
    for (int b = tid; b < NB; b += 256) cnt[b] = 0;
    __syncthreads();
    for (int e = e0 + tid; e < e1; e += 256)
        atomicAdd(&cnt[dst[e] >> BSHIFT], 1);
    __syncthreads();
    for (int b = tid; b < NB; b += 256) {
        int c = cnt[b];
        base[b] = c ? atomicAdd(&bucketCursor[b * CPAD], c) : 0;
        cnt[b] = 0;
    }
    __syncthreads();
    for (int e = e0 + tid; e < e1; e += 256) {
        int d = dst[e];
        int b = d >> BSHIFT;
        int off = atomicAdd(&cnt[b], 1);
        ebuf[base[b] + off] = (src[e] << BSHIFT) | (d & ((1 << BSHIFT) - 1));
    }
}

// ---- pass 4: per-bucket CSR build + rowptr + dinv (all LDS atomics) ---------
__global__ __launch_bounds__(256) void build_kernel(const int* __restrict__ ebuf,
                                                    const int* __restrict__ bucketBase,
                                                    int* __restrict__ rowptr,
                                                    int* __restrict__ csr,
                                                    float* __restrict__ dinv, int n) {
    __shared__ int hist[512];
    __shared__ int cur[512];
    __shared__ int ps[256];
    int tid = threadIdx.x;
    int b = blockIdx.x;
    int nodeBase = b << BSHIFT;
    int ebeg = bucketBase[b], eend = bucketBase[b + 1];
    hist[tid] = 0; hist[tid + 256] = 0;
    cur[tid] = 0;  cur[tid + 256] = 0;
    __syncthreads();
    for (int e = ebeg + tid; e < eend; e += 256)
        atomicAdd(&hist[ebuf[e] & 511], 1);
    __syncthreads();
    int s0 = hist[2 * tid], s1 = hist[2 * tid + 1];
    ps[tid] = s0 + s1;
    __syncthreads();
    for (int off = 1; off < 256; off <<= 1) {
        int t = (tid >= off) ? ps[tid - off] : 0;
        __syncthreads();
        ps[tid] += t;
        __syncthreads();
    }
    int ex = ps[tid] - (s0 + s1);   // exclusive prefix for node 2*tid
    int i0 = 2 * tid, i1 = 2 * tid + 1;
    if (nodeBase + i0 < n) {
        rowptr[nodeBase + i0] = ebeg + ex;
        dinv[nodeBase + i0] = rsqrtf((float)s0 + 1.0f);
    }
    if (nodeBase + i1 < n) {
        rowptr[nodeBase + i1] = ebeg + ex + s0;
        dinv[nodeBase + i1] = rsqrtf((float)s1 + 1.0f);
    }
    hist[i0] = ex;
    hist[i1] = ex + s0;
    __syncthreads();
    for (int e = ebeg + tid; e < eend; e += 256) {
        int p = ebuf[e];
        int d = p & 511;
        int pos = hist[d] + atomicAdd(&cur[d], 1);
        csr[ebeg + pos] = p >> BSHIFT;   // p >= 0, logical shift
    }
}

// ---- xs = x * dinv ----------------------------------------------------------
__global__ __launch_bounds__(256) void xs_kernel(const float* __restrict__ x,
                                                 const float* __restrict__ dinv,
                                                 float* __restrict__ xs, int total) {
    int g = blockIdx.x * 256 + threadIdx.x;
    if (g < total) xs[g] = x[g] * dinv[g / INDIM];
}

// ------- gather layer-1 in INPUT space ---------------------------------------
// aggx[i] = dinv[i] * (xs[i] + sum_nbr xs[nbr]); 12 lane-groups of 5 lanes,
// each group covers one neighbor row (5 float4 chunks of 20 floats).
__global__ __launch_bounds__(256) void gather1_kernel(const int* __restrict__ rowptr,
                                                      const int* __restrict__ csr,
                                                      const float* __restrict__ xs,
                                                      const float* __restrict__ dinv,
                                                      float* __restrict__ aggx, int n) {
    int tid = threadIdx.x;
    int w = (blockIdx.x * 256 + tid) >> 6;
    int lane = tid & 63;
    if (w >= n) return;
    int rg = lane / 5;
    int ch = lane - rg * 5;
    bool act = lane < 60;
    float4 acc = make_float4(0.f, 0.f, 0.f, 0.f);
    if (rg == 0)
        acc = *reinterpret_cast<const float4*>(&xs[(size_t)w * INDIM + ch * 4]);
    int beg = rowptr[w], end = rowptr[w + 1];
    for (int base = beg; base < end; base += 64) {
        int cnt = min(64, end - base);
        int myi = (lane < cnt) ? csr[base + lane] : 0;
        int k = 0;
        for (; k + 12 <= cnt; k += 12) {
            int nb = __shfl(myi, k + rg);
            if (act)
                acc = f4add(acc, *reinterpret_cast<const float4*>(
                                     &xs[(size_t)nb * INDIM + ch * 4]));
        }
        if (k < cnt) {
            int kk = k + rg;
            if (act && kk < cnt) {
                int nb = __shfl(myi, kk);
                acc = f4add(acc, *reinterpret_cast<const float4*>(
                                     &xs[(size_t)nb * INDIM + ch * 4]));
            }
        }
    }
    #define F4DOWN(v, d) make_float4(__shfl_down((v).x, d), __shfl_down((v).y, d), \
                                     __shfl_down((v).z, d), __shfl_down((v).w, d))
    acc = f4add(acc, F4DOWN(acc, 30));
    acc = f4add(acc, F4DOWN(acc, 15));
    float4 a5 = F4DOWN(acc, 5);
    float4 a10 = F4DOWN(acc, 10);
    acc = f4add(f4add(acc, a5), a10);
    if (lane < 5) {
        float dw = dinv[w];
        float4 o = make_float4(acc.x * dw, acc.y * dw, acc.z * dw, acc.w * dw);
        *reinterpret_cast<float4*>(&aggx[(size_t)w * INDIM + lane * 4]) = o;
    }
}

// ------- fused mm: v1 = relu(aggx@W1+b1); hs2 = (v1@W2)*dinv -----------------
__global__ __launch_bounds__(256) void mm12_kernel(const float* __restrict__ aggx,
                                                   const float* __restrict__ W1,
                                                   const float* __restrict__ b1,
                                                   const float* __restrict__ W2,
                                                   const float* __restrict__ dinv,
                                                   float* __restrict__ hs2, int n) {
    __shared__ float W1s[INDIM * HDIM];
    __shared__ float W2s[HDIM * HDIM];
    __shared__ float ax[4][INDIM];
    __shared__ float v1s[4][HDIM];
    int tid = threadIdx.x;
    for (int idx = tid; idx < INDIM * HDIM; idx += 256) W1s[idx] = W1[idx];
    for (int idx = tid; idx < HDIM * HDIM; idx += 256) W2s[idx] = W2[idx];
    int sub = tid >> 6;
    int f = tid & 63;
    int i00 = blockIdx.x * 16;
    for (int it = 0; it < 4; ++it) {
        int i0 = i00 + it * 4;
        __syncthreads();
        for (int idx = tid; idx < 4 * INDIM; idx += 256) {
            int node = i0 + idx / INDIM;
            ax[idx / INDIM][idx % INDIM] =
                (node < n) ? aggx[(size_t)node * INDIM + idx % INDIM] : 0.0f;
        }
        __syncthreads();
        float acc = b1[f];
        #pragma unroll
        for (int k = 0; k < INDIM; ++k) acc += ax[sub][k] * W1s[k * HDIM + f];
        v1s[sub][f] = fmaxf(acc, 0.0f);
        __syncthreads();
        int i = i0 + sub;
        if (i < n) {
            float acc2 = 0.0f;
            #pragma unroll
            for (int k = 0; k < HDIM; ++k) acc2 += v1s[sub][k] * W2s[k * HDIM + f];
            hs2[(size_t)i * HDIM + f] = acc2 * dinv[i];
        }
    }
}

// ------- gather layer-2 + fused mean partial ---------------------------------
// 4 lane-groups of 16; 4-deep unroll = 16 neighbor rows (4 KB) in flight/wave.
__global__ __launch_bounds__(256) void gather2_kernel(const int* __restrict__ rowptr,
                                                      const int* __restrict__ csr,
                                                      const float* __restrict__ hs2,
                                                      const float* __restrict__ dinv,
                                                      const float* __restrict__ b2,
                                                      float* __restrict__ gpart, int n) {
    __shared__ float4 shp[4][16];
    int tid = threadIdx.x;
    int wv = tid >> 6;
    int lane = tid & 63;
    int rg = lane >> 4;
    int ch = lane & 15;
    float4 b2c = *reinterpret_cast<const float4*>(&b2[ch * 4]);
    float4 vsum = make_float4(0.f, 0.f, 0.f, 0.f);
    int gw = blockIdx.x * 4 + wv;
    for (int w = gw; w < n; w += GB2 * 4) {
        float4 acc0 = make_float4(0.f, 0.f, 0.f, 0.f);
        float4 acc1 = make_float4(0.f, 0.f, 0.f, 0.f);
        float4 acc2 = make_float4(0.f, 0.f, 0.f, 0.f);
        float4 acc3 = make_float4(0.f, 0.f, 0.f, 0.f);
        if (rg == 0)
            acc0 = *reinterpret_cast<const float4*>(&hs2[(size_t)w * HDIM + ch * 4]);
        int beg = rowptr[w], end = rowptr[w + 1];
        for (int base = beg; base < end; base += 64) {
            int cnt = min(64, end - base);
            int myi = (lane < cnt) ? csr[base + lane] : 0;
            int k = 0;
            for (; k + 16 <= cnt; k += 16) {
                int nb0 = __shfl(myi, k + rg);
                int nb1 = __shfl(myi, k + 4 + rg);
                int nb2 = __shfl(myi, k + 8 + rg);
                int nb3 = __shfl(myi, k + 12 + rg);
                float4 v0 = *reinterpret_cast<const float4*>(&hs2[(size_t)nb0 * HDIM + ch * 4]);
                float4 v1 = *reinterpret_cast<const float4*>(&hs2[(size_t)nb1 * HDIM + ch * 4]);
                float4 v2 = *reinterpret_cast<const float4*>(&hs2[(size_t)nb2 * HDIM + ch * 4]);
                float4 v3 = *reinterpret_cast<const float4*>(&hs2[(size_t)nb3 * HDIM + ch * 4]);
                acc0 = f4add(acc0, v0);
                acc1 = f4add(acc1, v1);
                acc2 = f4add(acc2, v2);
                acc3 = f4add(acc3, v3);
            }
            for (; k + 8 <= cnt; k += 8) {
                int nb0 = __shfl(myi, k + rg);
                int nb1 = __shfl(myi, k + 4 + rg);
                float4 v0 = *reinterpret_cast<const float4*>(&hs2[(size_t)nb0 * HDIM + ch * 4]);
                float4 v1 = *reinterpret_cast<const float4*>(&hs2[(size_t)nb1 * HDIM + ch * 4]);
                acc0 = f4add(acc0, v0);
                acc1 = f4add(acc1, v1);
            }
            for (; k < cnt; k += 4) {
                int kk = k + rg;
                if (kk < cnt) {
                    int nb = __shfl(myi, kk);
                    acc0 = f4add(acc0, *reinterpret_cast<const float4*>(
                                           &hs2[(size_t)nb * HDIM + ch * 4]));
                }
            }
        }
        float4 acc = f4add(f4add(acc0, acc1), f4add(acc2, acc3));
        acc.x += __shfl_xor(acc.x, 16); acc.y += __shfl_xor(acc.y, 16);
        acc.z += __shfl_xor(acc.z, 16); acc.w += __shfl_xor(acc.w, 16);
        acc.x += __shfl_xor(acc.x, 32); acc.y += __shfl_xor(acc.y, 32);
        acc.z += __shfl_xor(acc.z, 32); acc.w += __shfl_xor(acc.w, 32);
        float dw = dinv[w];
        vsum.x += fmaxf(acc.x * dw + b2c.x, 0.0f);
        vsum.y += fmaxf(acc.y * dw + b2c.y, 0.0f);
        vsum.z += fmaxf(acc.z * dw + b2c.z, 0.0f);
        vsum.w += fmaxf(acc.w * dw + b2c.w, 0.0f);
    }
    if (rg == 0) shp[wv][ch] = vsum;
    __syncthreads();
    if (tid < 64) {
        const float* sp = (const float*)shp;
        float s = sp[tid] + sp[64 + tid] + sp[128 + tid] + sp[192 + tid];
        gpart[(size_t)blockIdx.x * HDIM + tid] = s;
    }
}

// ---- stage-2 parallel reduce: gpart[GB2][64] -> gpart2[GB2R][64] ------------
__global__ __launch_bounds__(256) void reduce2_kernel(const float* __restrict__ gpart,
                                                      float* __restrict__ gpart2) {
    __shared__ float lds[256];
    int tid = threadIdx.x;
    int q = tid >> 6;
    int f = tid & 63;
    const int rows = GB2 / GB2R;   // 32 rows per block
    int r0 = blockIdx.x * rows;
    float s = 0.0f;
    for (int r = r0 + q; r < r0 + rows; r += 4)
        s += gpart[(size_t)r * HDIM + f];
    lds[tid] = s;
    __syncthreads();
    if (tid < 64)
        gpart2[(size_t)blockIdx.x * HDIM + tid] =
            lds[tid] + lds[64 + tid] + lds[128 + tid] + lds[192 + tid];
}

// ---------------- final reduce + tiny MLP head --------------------------------
__global__ __launch_bounds__(256) void head_kernel(const float* __restrict__ gpart2,
                                                   const float* __restrict__ fcW1,
                                                   const float* __restrict__ fcb1,
                                                   const float* __restrict__ fcW2,
                                                   const float* __restrict__ fcb2,
                                                   float* __restrict__ out, int n) {
    __shared__ float lds[256];
    __shared__ float g[HDIM];
    __shared__ float t1[HDIM];
    int tid = threadIdx.x;
    int q = tid >> 6;
    int f = tid & 63;
    float s = 0.0f;
    for (int b = q; b < GB2R; b += 4) s += gpart2[(size_t)b * HDIM + f];
    lds[tid] = s;
    __syncthreads();
    if (tid < 64)
        g[tid] = (lds[tid] + lds[64 + tid] + lds[128 + tid] + lds[192 + tid]) *
                 (1.0f / (float)n);
    __syncthreads();
    if (tid < 64) {
        float acc = fcb1[tid];
        #pragma unroll
        for (int k = 0; k < HDIM; ++k) acc += g[k] * fcW1[k * HDIM + tid];
        t1[tid] = fmaxf(acc, 0.0f);
    }
    __syncthreads();
    if (tid < OUTDIM) {
        float acc = fcb2[tid];
        #pragma unroll
        for (int j = 0; j < HDIM; ++j) acc += t1[j] * fcW2[j * OUTDIM + tid];
        out[tid] = 1.0f / (1.0f + expf(-acc));
    }
}

extern "C" void kernel_launch(void* const* d_in, const int* in_sizes, int n_in,
                              void* d_out, int out_size, void* d_ws, size_t ws_size,
                              hipStream_t stream) {
    const float* x    = (const float*)d_in[0];
    const int*   ei   = (const int*)d_in[1];
    const float* W1   = (const float*)d_in[2];
    const float* b1   = (const float*)d_in[3];
    const float* W2   = (const float*)d_in[4];
    const float* b2   = (const float*)d_in[5];
    const float* fcW1 = (const float*)d_in[6];
    const float* fcb1 = (const float*)d_in[7];
    const float* fcW2 = (const float*)d_in[8];
    const float* fcb2 = (const float*)d_in[9];
    float* out = (float*)d_out;

    const int n = N_NODES;
    const int E = in_sizes[1] / 2;
    const int* src = ei;
    const int* dst = ei + E;

    char* ws = (char*)d_ws;
    size_t off = 0;
    auto alloc = [&](size_t bytes) -> void* {
        void* p = ws + off;
        off = (off + bytes + 255) & ~(size_t)255;
        return p;
    };
    float* dinv    = (float*)alloc((size_t)n * 4);
    int*   rowptr  = (int*)  alloc((size_t)(n + 1) * 4);
    int*   bCount  = (int*)  alloc((size_t)NB * CPAD * 4);
    int*   bBase   = (int*)  alloc((NB + 1) * 4);
    int*   bCursor = (int*)  alloc((size_t)NB * CPAD * 4);
    int*   csr     = (int*)  alloc((size_t)E * 4);
    int*   ebuf    = (int*)  alloc((size_t)E * 4);
    float* hs2     = (float*)alloc((size_t)n * HDIM * 4);
    float* xs      = (float*)alloc((size_t)n * INDIM * 4);
    float* aggx    = (float*)alloc((size_t)n * INDIM * 4);
    float* gpart   = (float*)alloc((size_t)GB2 * HDIM * 4);
    float* gpart2  = (float*)alloc((size_t)GB2R * HDIM * 4);
    (void)ws_size;

    hipMemsetAsync(bCount, 0, (size_t)NB * CPAD * 4, stream);

    // CSR build: hist -> scan -> partition -> per-bucket build (+rowptr +dinv)
    hist_kernel<<<512, 256, 0, stream>>>(dst, bCount, E);
    bscan_kernel<<<1, 256, 0, stream>>>(bCount, bBase, bCursor, rowptr, E);
    part_kernel<<<(E + CHUNK - 1) / CHUNK, 256, 0, stream>>>(src, dst, bCursor, ebuf, E);
    build_kernel<<<NB, 256, 0, stream>>>(ebuf, bBase, rowptr, csr, dinv, n);

    xs_kernel<<<(n * INDIM + 255) / 256, 256, 0, stream>>>(x, dinv, xs, n * INDIM);

    int g1blocks = (n * 64 + 255) / 256;
    gather1_kernel<<<g1blocks, 256, 0, stream>>>(rowptr, csr, xs, dinv, aggx, n);
    mm12_kernel<<<(n + 15) / 16, 256, 0, stream>>>(aggx, W1, b1, W2, dinv, hs2, n);
    gather2_kernel<<<GB2, 256, 0, stream>>>(rowptr, csr, hs2, dinv, b2, gpart, n);

    reduce2_kernel<<<GB2R, 256, 0, stream>>>(gpart, gpart2);
    head_kernel<<<1, 256, 0, stream>>>(gpart2, fcW1, fcb1, fcW2, fcb2, out, n);
}

// Round 10
// 361.273 us; speedup vs baseline: 1.9515x; 1.1941x over previous
//
#include <hip/hip_runtime.h>
#include <math.h>

#define N_NODES 100000
#define HDIM 64
#define INDIM 20
#define OUTDIM 128
#define GB2 2048    // gather2 grid blocks (4 waves each)
#define GB2R 64     // stage-2 reduction blocks
#define BSHIFT 9    // 512 nodes per bucket
#define NB 196      // ceil(100000 / 512)
#define CHUNK 3072  // edges per partition block
#define CPAD 16     // ints per padded counter (one 64B line)

typedef unsigned int  u32;
typedef unsigned short u16;

__device__ __forceinline__ float4 f4add(float4 a, float4 b) {
    return make_float4(a.x + b.x, a.y + b.y, a.z + b.z, a.w + b.w);
}
__device__ __forceinline__ float bl(u32 u) {   // low bf16 -> f32
    return __uint_as_float(u << 16);
}
__device__ __forceinline__ float bh(u32 u) {   // high bf16 -> f32
    return __uint_as_float(u & 0xffff0000u);
}
__device__ __forceinline__ u16 f2b(float f) {  // f32 -> bf16 (RNE)
    u32 u = __float_as_uint(f);
    return (u16)((u + 0x7fffu + ((u >> 16) & 1u)) >> 16);
}

// ---- pass 1: coarse histogram of dst buckets (LDS-privatized) ---------------
__global__ __launch_bounds__(256) void hist_kernel(const int* __restrict__ dst,
                                                   int* __restrict__ bucketCount, int E) {
    __shared__ int h[NB];
    int tid = threadIdx.x;
    for (int b = tid; b < NB; b += 256) h[b] = 0;
    __syncthreads();
    for (int e = blockIdx.x * 256 + tid; e < E; e += gridDim.x * 256)
        atomicAdd(&h[dst[e] >> BSHIFT], 1);
    __syncthreads();
    for (int b = tid; b < NB; b += 256)
        if (h[b]) atomicAdd(&bucketCount[b * CPAD], h[b]);
}

// ---- pass 2: scan bucket counts -> bases + working cursors ------------------
__global__ __launch_bounds__(256) void bscan_kernel(const int* __restrict__ bucketCount,
                                                    int* __restrict__ bucketBase,
                                                    int* __restrict__ bucketCursor,
                                                    int* __restrict__ rowptr, int E) {
    __shared__ int s[256];
    int tid = threadIdx.x;
    int v = (tid < NB) ? bucketCount[tid * CPAD] : 0;
    s[tid] = v;
    __syncthreads();
    for (int off = 1; off < 256; off <<= 1) {
        int t = (tid >= off) ? s[tid - off] : 0;
        __syncthreads();
        s[tid] += t;
        __syncthreads();
    }
    if (tid < NB) {
        int base = s[tid] - v;
        bucketBase[tid] = base;
        bucketCursor[tid * CPAD] = base;
    }
    if (tid == 0) { bucketBase[NB] = E; rowptr[N_NODES] = E; }
}

// ---- pass 3: partition edges into bucket-grouped packed ebuf ----------------
// packed = (src << 9) | (dst & 511); src < 2^17 so fits 26 bits.
__global__ __launch_bounds__(256) void part_kernel(const int* __restrict__ src,
                                                   const int* __restrict__ dst,
                                                   int* __restrict__ bucketCursor,
                                                   int* __restrict__ ebuf, int E) {
    __shared__ int cnt[NB];
    __shared__ int base[NB];
    int tid = threadIdx.x;
    int e0 = blockIdx.x * CHUNK;
    int e1 = min(E, e0 + CHUNK);
    for (int b = tid; b < NB; b += 256) cnt[b] = 0;
    __syncthreads();
    for (int e = e0 + tid; e < e1; e += 256)
        atomicAdd(&cnt[dst[e] >> BSHIFT], 1);
    __syncthreads();
    for (int b = tid; b < NB; b += 256) {
        int c = cnt[b];
        base[b] = c ? atomicAdd(&bucketCursor[b * CPAD], c) : 0;
        cnt[b] = 0;
    }
    __syncthreads();
    for (int e = e0 + tid; e < e1; e += 256) {
        int d = dst[e];
        int b = d >> BSHIFT;
        int off = atomicAdd(&cnt[b], 1);
        ebuf[base[b] + off] = (src[e] << BSHIFT) | (d & ((1 << BSHIFT) - 1));
    }
}

// ---- pass 4: per-bucket CSR build + rowptr + dinv (all LDS atomics) ---------
__global__ __launch_bounds__(256) void build_kernel(const int* __restrict__ ebuf,
                                                    const int* __restrict__ bucketBase,
                                                    int* __restrict__ rowptr,
                                                    int* __restrict__ csr,
                                                    float* __restrict__ dinv, int n) {
    __shared__ int hist[512];
    __shared__ int cur[512];
    __shared__ int ps[256];
    int tid = threadIdx.x;
    int b = blockIdx.x;
    int nodeBase = b << BSHIFT;
    int ebeg = bucketBase[b], eend = bucketBase[b + 1];
    hist[tid] = 0; hist[tid + 256] = 0;
    cur[tid] = 0;  cur[tid + 256] = 0;
    __syncthreads();
    for (int e = ebeg + tid; e < eend; e += 256)
        atomicAdd(&hist[ebuf[e] & 511], 1);
    __syncthreads();
    int s0 = hist[2 * tid], s1 = hist[2 * tid + 1];
    ps[tid] = s0 + s1;
    __syncthreads();
    for (int off = 1; off < 256; off <<= 1) {
        int t = (tid >= off) ? ps[tid - off] : 0;
        __syncthreads();
        ps[tid] += t;
        __syncthreads();
    }
    int ex = ps[tid] - (s0 + s1);   // exclusive prefix for node 2*tid
    int i0 = 2 * tid, i1 = 2 * tid + 1;
    if (nodeBase + i0 < n) {
        rowptr[nodeBase + i0] = ebeg + ex;
        dinv[nodeBase + i0] = rsqrtf((float)s0 + 1.0f);
    }
    if (nodeBase + i1 < n) {
        rowptr[nodeBase + i1] = ebeg + ex + s0;
        dinv[nodeBase + i1] = rsqrtf((float)s1 + 1.0f);
    }
    hist[i0] = ex;
    hist[i1] = ex + s0;
    __syncthreads();
    for (int e = ebeg + tid; e < eend; e += 256) {
        int p = ebuf[e];
        int d = p & 511;
        int pos = hist[d] + atomicAdd(&cur[d], 1);
        csr[ebeg + pos] = p >> BSHIFT;   // p >= 0, logical shift
    }
}

// ---- xs = bf16(x * dinv) ----------------------------------------------------
__global__ __launch_bounds__(256) void xs_kernel(const float* __restrict__ x,
                                                 const float* __restrict__ dinv,
                                                 u16* __restrict__ xsb, int total) {
    int g = blockIdx.x * 256 + threadIdx.x;
    if (g < total) xsb[g] = f2b(x[g] * dinv[g / INDIM]);
}

// ------- gather layer-1 in INPUT space (bf16 rows, 40 B) ---------------------
// aggx[i] = dinv[i] * (xs[i] + sum_nbr xs[nbr]); 12 lane-groups of 5 lanes,
// each lane loads uint2 = 4 bf16 features of one neighbor row.
__global__ __launch_bounds__(256) void gather1_kernel(const int* __restrict__ rowptr,
                                                      const int* __restrict__ csr,
                                                      const u16* __restrict__ xsb,
                                                      const float* __restrict__ dinv,
                                                      float* __restrict__ aggx, int n) {
    int tid = threadIdx.x;
    int w = (blockIdx.x * 256 + tid) >> 6;
    int lane = tid & 63;
    if (w >= n) return;
    int rg = lane / 5;
    int ch = lane - rg * 5;     // 4-feature chunk (8 B)
    bool act = lane < 60;
    float4 acc = make_float4(0.f, 0.f, 0.f, 0.f);
    if (rg == 0) {
        uint2 u = *reinterpret_cast<const uint2*>(xsb + (size_t)w * INDIM + ch * 4);
        acc = make_float4(bl(u.x), bh(u.x), bl(u.y), bh(u.y));
    }
    int beg = rowptr[w], end = rowptr[w + 1];
    for (int base = beg; base < end; base += 64) {
        int cnt = min(64, end - base);
        int myi = (lane < cnt) ? csr[base + lane] : 0;
        int k = 0;
        for (; k + 12 <= cnt; k += 12) {
            int nb = __shfl(myi, k + rg);
            if (act) {
                uint2 u = *reinterpret_cast<const uint2*>(xsb + (size_t)nb * INDIM + ch * 4);
                acc = f4add(acc, make_float4(bl(u.x), bh(u.x), bl(u.y), bh(u.y)));
            }
        }
        if (k < cnt) {
            int kk = k + rg;
            if (act && kk < cnt) {
                int nb = __shfl(myi, kk);
                uint2 u = *reinterpret_cast<const uint2*>(xsb + (size_t)nb * INDIM + ch * 4);
                acc = f4add(acc, make_float4(bl(u.x), bh(u.x), bl(u.y), bh(u.y)));
            }
        }
    }
    #define F4DOWN(v, d) make_float4(__shfl_down((v).x, d), __shfl_down((v).y, d), \
                                     __shfl_down((v).z, d), __shfl_down((v).w, d))
    acc = f4add(acc, F4DOWN(acc, 30));
    acc = f4add(acc, F4DOWN(acc, 15));
    float4 a5 = F4DOWN(acc, 5);
    float4 a10 = F4DOWN(acc, 10);
    acc = f4add(f4add(acc, a5), a10);
    if (lane < 5) {
        float dw = dinv[w];
        float4 o = make_float4(acc.x * dw, acc.y * dw, acc.z * dw, acc.w * dw);
        *reinterpret_cast<float4*>(&aggx[(size_t)w * INDIM + lane * 4]) = o;
    }
}

// ------- fused mm: v1 = relu(aggx@W1+b1); hs2b = bf16((v1@W2)*dinv) ----------
__global__ __launch_bounds__(256) void mm12_kernel(const float* __restrict__ aggx,
                                                   const float* __restrict__ W1,
                                                   const float* __restrict__ b1,
                                                   const float* __restrict__ W2,
                                                   const float* __restrict__ dinv,
                                                   u16* __restrict__ hs2b, int n) {
    __shared__ float W1s[INDIM * HDIM];
    __shared__ float W2s[HDIM * HDIM];
    __shared__ float ax[4][INDIM];
    __shared__ float v1s[4][HDIM];
    int tid = threadIdx.x;
    for (int idx = tid; idx < INDIM * HDIM; idx += 256) W1s[idx] = W1[idx];
    for (int idx = tid; idx < HDIM * HDIM; idx += 256) W2s[idx] = W2[idx];
    int sub = tid >> 6;
    int f = tid & 63;
    int i00 = blockIdx.x * 16;
    for (int it = 0; it < 4; ++it) {
        int i0 = i00 + it * 4;
        __syncthreads();
        for (int idx = tid; idx < 4 * INDIM; idx += 256) {
            int node = i0 + idx / INDIM;
            ax[idx / INDIM][idx % INDIM] =
                (node < n) ? aggx[(size_t)node * INDIM + idx % INDIM] : 0.0f;
        }
        __syncthreads();
        float acc = b1[f];
        #pragma unroll
        for (int k = 0; k < INDIM; ++k) acc += ax[sub][k] * W1s[k * HDIM + f];
        v1s[sub][f] = fmaxf(acc, 0.0f);
        __syncthreads();
        int i = i0 + sub;
        if (i < n) {
            float acc2 = 0.0f;
            #pragma unroll
            for (int k = 0; k < HDIM; ++k) acc2 += v1s[sub][k] * W2s[k * HDIM + f];
            hs2b[(size_t)i * HDIM + f] = f2b(acc2 * dinv[i]);
        }
    }
}

// ------- gather layer-2 (bf16 rows, 128 B) + fused mean partial --------------
// 8 lane-groups of 8; each lane loads uint4 = 8 bf16 features of one row.
// 2-deep unroll = 16 neighbor rows (2 KB) in flight per wave.
#define ADD8(acc, v) do { \
    acc[0] += bl((v).x); acc[1] += bh((v).x); \
    acc[2] += bl((v).y); acc[3] += bh((v).y); \
    acc[4] += bl((v).z); acc[5] += bh((v).z); \
    acc[6] += bl((v).w); acc[7] += bh((v).w); } while (0)

__global__ __launch_bounds__(256) void gather2_kernel(const int* __restrict__ rowptr,
                                                      const int* __restrict__ csr,
                                                      const u16* __restrict__ hs2b,
                                                      const float* __restrict__ dinv,
                                                      const float* __restrict__ b2,
                                                      float* __restrict__ gpart, int n) {
    __shared__ float shp[4][64];
    int tid = threadIdx.x;
    int wv = tid >> 6;
    int lane = tid & 63;
    int rg = lane >> 3;        // 0..7
    int ch = lane & 7;         // 8-feature chunk (16 B)
    float b2c[8];
    #pragma unroll
    for (int j = 0; j < 8; ++j) b2c[j] = b2[ch * 8 + j];
    float vsum[8] = {0.f, 0.f, 0.f, 0.f, 0.f, 0.f, 0.f, 0.f};
    int gw = blockIdx.x * 4 + wv;
    for (int w = gw; w < n; w += GB2 * 4) {
        float acc[8] = {0.f, 0.f, 0.f, 0.f, 0.f, 0.f, 0.f, 0.f};
        if (rg == 0) {
            uint4 v = *reinterpret_cast<const uint4*>(hs2b + (size_t)w * HDIM + ch * 8);
            ADD8(acc, v);
        }
        int beg = rowptr[w], end = rowptr[w + 1];
        for (int base = beg; base < end; base += 64) {
            int cnt = min(64, end - base);
            int myi = (lane < cnt) ? csr[base + lane] : 0;
            int k = 0;
            for (; k + 16 <= cnt; k += 16) {
                int nb0 = __shfl(myi, k + rg);
                int nb1 = __shfl(myi, k + 8 + rg);
                uint4 v0 = *reinterpret_cast<const uint4*>(hs2b + (size_t)nb0 * HDIM + ch * 8);
                uint4 v1 = *reinterpret_cast<const uint4*>(hs2b + (size_t)nb1 * HDIM + ch * 8);
                ADD8(acc, v0);
                ADD8(acc, v1);
            }
            for (; k < cnt; k += 8) {
                int kk = k + rg;
                if (kk < cnt) {
                    int nb = __shfl(myi, kk);
                    uint4 v = *reinterpret_cast<const uint4*>(hs2b + (size_t)nb * HDIM + ch * 8);
                    ADD8(acc, v);
                }
            }
        }
        #pragma unroll
        for (int j = 0; j < 8; ++j) {
            acc[j] += __shfl_xor(acc[j], 8);
            acc[j] += __shfl_xor(acc[j], 16);
            acc[j] += __shfl_xor(acc[j], 32);
        }
        float dw = dinv[w];
        #pragma unroll
        for (int j = 0; j < 8; ++j)
            vsum[j] += fmaxf(acc[j] * dw + b2c[j], 0.0f);
    }
    if (rg == 0) {
        #pragma unroll
        for (int j = 0; j < 8; ++j) shp[wv][ch * 8 + j] = vsum[j];
    }
    __syncthreads();
    if (tid < 64)
        gpart[(size_t)blockIdx.x * HDIM + tid] =
            shp[0][tid] + shp[1][tid] + shp[2][tid] + shp[3][tid];
}

// ---- stage-2 parallel reduce: gpart[GB2][64] -> gpart2[GB2R][64] ------------
__global__ __launch_bounds__(256) void reduce2_kernel(const float* __restrict__ gpart,
                                                      float* __restrict__ gpart2) {
    __shared__ float lds[256];
    int tid = threadIdx.x;
    int q = tid >> 6;
    int f = tid & 63;
    const int rows = GB2 / GB2R;   // 32 rows per block
    int r0 = blockIdx.x * rows;
    float s = 0.0f;
    for (int r = r0 + q; r < r0 + rows; r += 4)
        s += gpart[(size_t)r * HDIM + f];
    lds[tid] = s;
    __syncthreads();
    if (tid < 64)
        gpart2[(size_t)blockIdx.x * HDIM + tid] =
            lds[tid] + lds[64 + tid] + lds[128 + tid] + lds[192 + tid];
}

// ---------------- final reduce + tiny MLP head --------------------------------
__global__ __launch_bounds__(256) void head_kernel(const float* __restrict__ gpart2,
                                                   const float* __restrict__ fcW1,
                                                   const float* __restrict__ fcb1,
                                                   const float* __restrict__ fcW2,
                                                   const float* __restrict__ fcb2,
                                                   float* __restrict__ out, int n) {
    __shared__ float lds[256];
    __shared__ float g[HDIM];
    __shared__ float t1[HDIM];
    int tid = threadIdx.x;
    int q = tid >> 6;
    int f = tid & 63;
    float s = 0.0f;
    for (int b = q; b < GB2R; b += 4) s += gpart2[(size_t)b * HDIM + f];
    lds[tid] = s;
    __syncthreads();
    if (tid < 64)
        g[tid] = (lds[tid] + lds[64 + tid] + lds[128 + tid] + lds[192 + tid]) *
                 (1.0f / (float)n);
    __syncthreads();
    if (tid < 64) {
        float acc = fcb1[tid];
        #pragma unroll
        for (int k = 0; k < HDIM; ++k) acc += g[k] * fcW1[k * HDIM + tid];
        t1[tid] = fmaxf(acc, 0.0f);
    }
    __syncthreads();
    if (tid < OUTDIM) {
        float acc = fcb2[tid];
        #pragma unroll
        for (int j = 0; j < HDIM; ++j) acc += t1[j] * fcW2[j * OUTDIM + tid];
        out[tid] = 1.0f / (1.0f + expf(-acc));
    }
}

extern "C" void kernel_launch(void* const* d_in, const int* in_sizes, int n_in,
                              void* d_out, int out_size, void* d_ws, size_t ws_size,
                              hipStream_t stream) {
    const float* x    = (const float*)d_in[0];
    const int*   ei   = (const int*)d_in[1];
    const float* W1   = (const float*)d_in[2];
    const float* b1   = (const float*)d_in[3];
    const float* W2   = (const float*)d_in[4];
    const float* b2   = (const float*)d_in[5];
    const float* fcW1 = (const float*)d_in[6];
    const float* fcb1 = (const float*)d_in[7];
    const float* fcW2 = (const float*)d_in[8];
    const float* fcb2 = (const float*)d_in[9];
    float* out = (float*)d_out;

    const int n = N_NODES;
    const int E = in_sizes[1] / 2;
    const int* src = ei;
    const int* dst = ei + E;

    char* ws = (char*)d_ws;
    size_t off = 0;
    auto alloc = [&](size_t bytes) -> void* {
        void* p = ws + off;
        off = (off + bytes + 255) & ~(size_t)255;
        return p;
    };
    float* dinv    = (float*)alloc((size_t)n * 4);
    int*   rowptr  = (int*)  alloc((size_t)(n + 1) * 4);
    int*   bCount  = (int*)  alloc((size_t)NB * CPAD * 4);
    int*   bBase   = (int*)  alloc((NB + 1) * 4);
    int*   bCursor = (int*)  alloc((size_t)NB * CPAD * 4);
    int*   csr     = (int*)  alloc((size_t)E * 4);
    int*   ebuf    = (int*)  alloc((size_t)E * 4);
    u16*   hs2b    = (u16*)  alloc((size_t)n * HDIM * 2);
    u16*   xsb     = (u16*)  alloc((size_t)n * INDIM * 2);
    float* aggx    = (float*)alloc((size_t)n * INDIM * 4);
    float* gpart   = (float*)alloc((size_t)GB2 * HDIM * 4);
    float* gpart2  = (float*)alloc((size_t)GB2R * HDIM * 4);
    (void)ws_size;

    hipMemsetAsync(bCount, 0, (size_t)NB * CPAD * 4, stream);

    // CSR build: hist -> scan -> partition -> per-bucket build (+rowptr +dinv)
    hist_kernel<<<512, 256, 0, stream>>>(dst, bCount, E);
    bscan_kernel<<<1, 256, 0, stream>>>(bCount, bBase, bCursor, rowptr, E);
    part_kernel<<<(E + CHUNK - 1) / CHUNK, 256, 0, stream>>>(src, dst, bCursor, ebuf, E);
    build_kernel<<<NB, 256, 0, stream>>>(ebuf, bBase, rowptr, csr, dinv, n);

    xs_kernel<<<(n * INDIM + 255) / 256, 256, 0, stream>>>(x, dinv, xsb, n * INDIM);

    int g1blocks = (n * 64 + 255) / 256;
    gather1_kernel<<<g1blocks, 256, 0, stream>>>(rowptr, csr, xsb, dinv, aggx, n);
    mm12_kernel<<<(n + 15) / 16, 256, 0, stream>>>(aggx, W1, b1, W2, dinv, hs2b, n);
    gather2_kernel<<<GB2, 256, 0, stream>>>(rowptr, csr, hs2b, dinv, b2, gpart, n);

    reduce2_kernel<<<GB2R, 256, 0, stream>>>(gpart, gpart2);
    head_kernel<<<1, 256, 0, stream>>>(gpart2, fcW1, fcb1, fcW2, fcb2, out, n);
}

// Round 11
// 315.340 us; speedup vs baseline: 2.2357x; 1.1457x over previous
//
#include <hip/hip_runtime.h>
#include <math.h>

#define N_NODES 100000
#define HDIM 64
#define INDIM 20
#define OUTDIM 128
#define GB2 2048    // gather2 grid blocks (4 waves each)
#define GB2R 64     // stage-2 reduction blocks
#define BSHIFT 9    // 512 nodes per bucket
#define NB 196      // ceil(100000 / 512)
#define CHUNK 3072  // edges per partition block
#define EPT 12      // edges per thread in part (CHUNK/256)
#define CPAD 16     // ints per padded counter (one 64B line)

typedef unsigned int  u32;
typedef unsigned short u16;
typedef unsigned char u8;
typedef __attribute__((ext_vector_type(8))) short short8;
typedef __attribute__((ext_vector_type(4))) float f32x4;

__device__ __forceinline__ float4 f4add(float4 a, float4 b) {
    return make_float4(a.x + b.x, a.y + b.y, a.z + b.z, a.w + b.w);
}
__device__ __forceinline__ float bl(u32 u) {   // low bf16 -> f32
    return __uint_as_float(u << 16);
}
__device__ __forceinline__ float bh(u32 u) {   // high bf16 -> f32
    return __uint_as_float(u & 0xffff0000u);
}
__device__ __forceinline__ u16 f2b(float f) {  // f32 -> bf16 (RNE)
    u32 u = __float_as_uint(f);
    return (u16)((u + 0x7fffu + ((u >> 16) & 1u)) >> 16);
}

// ---- pass 1: coarse histogram of dst buckets (LDS-privatized) ---------------
__global__ __launch_bounds__(256) void hist_kernel(const int* __restrict__ dst,
                                                   int* __restrict__ bucketCount, int E) {
    __shared__ int h[NB];
    int tid = threadIdx.x;
    for (int b = tid; b < NB; b += 256) h[b] = 0;
    __syncthreads();
    for (int e = blockIdx.x * 256 + tid; e < E; e += gridDim.x * 256)
        atomicAdd(&h[dst[e] >> BSHIFT], 1);
    __syncthreads();
    for (int b = tid; b < NB; b += 256)
        if (h[b]) atomicAdd(&bucketCount[b * CPAD], h[b]);
}

// ---- pass 2: scan bucket counts -> bases + working cursors ------------------
__global__ __launch_bounds__(256) void bscan_kernel(const int* __restrict__ bucketCount,
                                                    int* __restrict__ bucketBase,
                                                    int* __restrict__ bucketCursor,
                                                    int* __restrict__ rowptr, int E) {
    __shared__ int s[256];
    int tid = threadIdx.x;
    int v = (tid < NB) ? bucketCount[tid * CPAD] : 0;
    s[tid] = v;
    __syncthreads();
    for (int off = 1; off < 256; off <<= 1) {
        int t = (tid >= off) ? s[tid - off] : 0;
        __syncthreads();
        s[tid] += t;
        __syncthreads();
    }
    if (tid < NB) {
        int base = s[tid] - v;
        bucketBase[tid] = base;
        bucketCursor[tid * CPAD] = base;
    }
    if (tid == 0) { bucketBase[NB] = E; rowptr[N_NODES] = E; }
}

// ---- pass 3: partition edges into bucket-grouped packed ebuf ----------------
// Edges carried in registers; chunk staged in LDS grouped by bucket; each
// bucket run written to global COALESCED (full-line writes).
__global__ __launch_bounds__(256) void part_kernel(const int* __restrict__ src,
                                                   const int* __restrict__ dst,
                                                   int* __restrict__ bucketCursor,
                                                   int* __restrict__ ebuf, int E) {
    __shared__ int cnt[NB];
    __shared__ int lofs[NB];
    __shared__ int gbase[NB];
    __shared__ int ps[256];
    __shared__ int stage[CHUNK];
    __shared__ u8  sbid[CHUNK];
    int tid = threadIdx.x;
    int e0 = blockIdx.x * CHUNK;
    int e1 = min(E, e0 + CHUNK);
    for (int b = tid; b < NB; b += 256) cnt[b] = 0;
    __syncthreads();
    int myb[EPT];
    int myp[EPT];
    #pragma unroll
    for (int j = 0; j < EPT; ++j) {
        int e = e0 + j * 256 + tid;
        if (e < e1) {
            int d = dst[e];
            int b = d >> BSHIFT;
            myb[j] = b;
            myp[j] = (src[e] << BSHIFT) | (d & ((1 << BSHIFT) - 1));
            atomicAdd(&cnt[b], 1);
        } else myb[j] = -1;
    }
    __syncthreads();
    int c = (tid < NB) ? cnt[tid] : 0;
    ps[tid] = c;
    __syncthreads();
    for (int off = 1; off < 256; off <<= 1) {
        int t = (tid >= off) ? ps[tid - off] : 0;
        __syncthreads();
        ps[tid] += t;
        __syncthreads();
    }
    if (tid < NB) {
        lofs[tid] = ps[tid] - c;                                  // local exclusive
        gbase[tid] = c ? atomicAdd(&bucketCursor[tid * CPAD], c) : 0;
        cnt[tid] = 0;                                             // reuse as cursor
    }
    __syncthreads();
    #pragma unroll
    for (int j = 0; j < EPT; ++j) {
        int b = myb[j];
        if (b >= 0) {
            int off = atomicAdd(&cnt[b], 1);
            int p = lofs[b] + off;
            stage[p] = myp[j];
            sbid[p] = (u8)b;
        }
    }
    __syncthreads();
    int total = e1 - e0;
    for (int i = tid; i < total; i += 256) {
        int b = sbid[i];
        ebuf[gbase[b] + (i - lofs[b])] = stage[i];                // coalesced per run
    }
}

// ---- pass 4: per-bucket CSR build + rowptr + dinv (all LDS atomics) ---------
__global__ __launch_bounds__(256) void build_kernel(const int* __restrict__ ebuf,
                                                    const int* __restrict__ bucketBase,
                                                    int* __restrict__ rowptr,
                                                    int* __restrict__ csr,
                                                    float* __restrict__ dinv, int n) {
    __shared__ int hist[512];
    __shared__ int cur[512];
    __shared__ int ps[256];
    int tid = threadIdx.x;
    int b = blockIdx.x;
    int nodeBase = b << BSHIFT;
    int ebeg = bucketBase[b], eend = bucketBase[b + 1];
    hist[tid] = 0; hist[tid + 256] = 0;
    cur[tid] = 0;  cur[tid + 256] = 0;
    __syncthreads();
    for (int e = ebeg + tid; e < eend; e += 256)
        atomicAdd(&hist[ebuf[e] & 511], 1);
    __syncthreads();
    int s0 = hist[2 * tid], s1 = hist[2 * tid + 1];
    ps[tid] = s0 + s1;
    __syncthreads();
    for (int off = 1; off < 256; off <<= 1) {
        int t = (tid >= off) ? ps[tid - off] : 0;
        __syncthreads();
        ps[tid] += t;
        __syncthreads();
    }
    int ex = ps[tid] - (s0 + s1);   // exclusive prefix for node 2*tid
    int i0 = 2 * tid, i1 = 2 * tid + 1;
    if (nodeBase + i0 < n) {
        rowptr[nodeBase + i0] = ebeg + ex;
        dinv[nodeBase + i0] = rsqrtf((float)s0 + 1.0f);
    }
    if (nodeBase + i1 < n) {
        rowptr[nodeBase + i1] = ebeg + ex + s0;
        dinv[nodeBase + i1] = rsqrtf((float)s1 + 1.0f);
    }
    hist[i0] = ex;
    hist[i1] = ex + s0;
    __syncthreads();
    for (int e = ebeg + tid; e < eend; e += 256) {
        int p = ebuf[e];
        int d = p & 511;
        int pos = hist[d] + atomicAdd(&cur[d], 1);
        csr[ebeg + pos] = p >> BSHIFT;   // p >= 0, logical shift
    }
}

// ---- xs = bf16(x * dinv) ----------------------------------------------------
__global__ __launch_bounds__(256) void xs_kernel(const float* __restrict__ x,
                                                 const float* __restrict__ dinv,
                                                 u16* __restrict__ xsb, int total) {
    int g = blockIdx.x * 256 + threadIdx.x;
    if (g < total) xsb[g] = f2b(x[g] * dinv[g / INDIM]);
}

// ------- gather layer-1 in INPUT space (bf16 rows, 40 B) ---------------------
__global__ __launch_bounds__(256) void gather1_kernel(const int* __restrict__ rowptr,
                                                      const int* __restrict__ csr,
                                                      const u16* __restrict__ xsb,
                                                      const float* __restrict__ dinv,
                                                      float* __restrict__ aggx, int n) {
    int tid = threadIdx.x;
    int w = (blockIdx.x * 256 + tid) >> 6;
    int lane = tid & 63;
    if (w >= n) return;
    int rg = lane / 5;
    int ch = lane - rg * 5;     // 4-feature chunk (8 B)
    bool act = lane < 60;
    float4 acc = make_float4(0.f, 0.f, 0.f, 0.f);
    if (rg == 0) {
        uint2 u = *reinterpret_cast<const uint2*>(xsb + (size_t)w * INDIM + ch * 4);
        acc = make_float4(bl(u.x), bh(u.x), bl(u.y), bh(u.y));
    }
    int beg = rowptr[w], end = rowptr[w + 1];
    for (int base = beg; base < end; base += 64) {
        int cnt = min(64, end - base);
        int myi = (lane < cnt) ? csr[base + lane] : 0;
        int k = 0;
        for (; k + 12 <= cnt; k += 12) {
            int nb = __shfl(myi, k + rg);
            if (act) {
                uint2 u = *reinterpret_cast<const uint2*>(xsb + (size_t)nb * INDIM + ch * 4);
                acc = f4add(acc, make_float4(bl(u.x), bh(u.x), bl(u.y), bh(u.y)));
            }
        }
        if (k < cnt) {
            int kk = k + rg;
            if (act && kk < cnt) {
                int nb = __shfl(myi, kk);
                uint2 u = *reinterpret_cast<const uint2*>(xsb + (size_t)nb * INDIM + ch * 4);
                acc = f4add(acc, make_float4(bl(u.x), bh(u.x), bl(u.y), bh(u.y)));
            }
        }
    }
    #define F4DOWN(v, d) make_float4(__shfl_down((v).x, d), __shfl_down((v).y, d), \
                                     __shfl_down((v).z, d), __shfl_down((v).w, d))
    acc = f4add(acc, F4DOWN(acc, 30));
    acc = f4add(acc, F4DOWN(acc, 15));
    float4 a5 = F4DOWN(acc, 5);
    float4 a10 = F4DOWN(acc, 10);
    acc = f4add(f4add(acc, a5), a10);
    if (lane < 5) {
        float dw = dinv[w];
        float4 o = make_float4(acc.x * dw, acc.y * dw, acc.z * dw, acc.w * dw);
        *reinterpret_cast<float4*>(&aggx[(size_t)w * INDIM + lane * 4]) = o;
    }
}

// ------- fused mm: v1 = relu(aggx@W1+b1) [VALU]; hs2b = bf16((v1@W2)*dinv) [MFMA]
// Block = 256 threads = 4 waves, covers 64 nodes. Stage 1 writes v1 as bf16 to
// LDS in MFMA-A-friendly layout; W2 lives as bf16 B-fragments in registers
// (loaded once per block); each wave runs a 16-node x 64-feat tile via
// 8x mfma_f32_16x16x32_bf16.
__global__ __launch_bounds__(256) void mm12_kernel(const float* __restrict__ aggx,
                                                   const float* __restrict__ W1,
                                                   const float* __restrict__ b1,
                                                   const float* __restrict__ W2,
                                                   const float* __restrict__ dinv,
                                                   u16* __restrict__ hs2b, int n) {
    __shared__ float W1s[INDIM * HDIM];   // 5 KB
    __shared__ float ax[4][INDIM];
    __shared__ u16 v1b[64][72];           // 64 nodes x 64 k bf16, pad to 72 (9.2 KB)
    __shared__ float dinvs[64];
    int tid = threadIdx.x;
    for (int idx = tid; idx < INDIM * HDIM; idx += 256) W1s[idx] = W1[idx];
    int i00 = blockIdx.x * 64;
    if (tid < 64) dinvs[tid] = (i00 + tid < n) ? dinv[i00 + tid] : 0.0f;

    // B-fragments: W2 (bf16) in registers. frag(kh,ft): k in [kh*32,kh*32+32),
    // feats in [ft*16, ft*16+16). Lane l holds B[k=kh*32+(l>>4)*8+i][ft*16+(l&15)].
    int lane = tid & 63;
    int col = lane & 15, kq = lane >> 4;
    short8 bfrag[2][4];
    #pragma unroll
    for (int kh = 0; kh < 2; ++kh)
        #pragma unroll
        for (int ft = 0; ft < 4; ++ft)
            #pragma unroll
            for (int i = 0; i < 8; ++i) {
                int k = kh * 32 + kq * 8 + i;
                bfrag[kh][ft][i] = (short)f2b(W2[k * HDIM + ft * 16 + col]);
            }

    int sub = tid >> 6, f = tid & 63;
    // stage 1: 16 passes x 4 nodes -> v1b (bf16)
    for (int p = 0; p < 16; ++p) {
        int i0 = i00 + p * 4;
        __syncthreads();
        for (int idx = tid; idx < 4 * INDIM; idx += 256) {
            int node = i0 + idx / INDIM;
            ax[idx / INDIM][idx % INDIM] =
                (node < n) ? aggx[(size_t)node * INDIM + idx % INDIM] : 0.0f;
        }
        __syncthreads();
        float acc = b1[f];
        #pragma unroll
        for (int k = 0; k < INDIM; ++k) acc += ax[sub][k] * W1s[k * HDIM + f];
        v1b[p * 4 + sub][f] = f2b(fmaxf(acc, 0.0f));
    }
    __syncthreads();

    // stage 2: wave wv handles nodes [wv*16, wv*16+16)
    int wv = tid >> 6;
    int nb0 = wv * 16;
    short8 afrag[2];
    #pragma unroll
    for (int kh = 0; kh < 2; ++kh) {
        const u16* ap = &v1b[nb0 + col][kh * 32 + kq * 8];   // 16B-aligned (144B rows)
        afrag[kh] = *reinterpret_cast<const short8*>(ap);
    }
    int gr0 = i00 + nb0;
    #pragma unroll
    for (int ft = 0; ft < 4; ++ft) {
        f32x4 acc = {0.f, 0.f, 0.f, 0.f};
        acc = __builtin_amdgcn_mfma_f32_16x16x32_bf16(afrag[0], bfrag[0][ft], acc, 0, 0, 0);
        acc = __builtin_amdgcn_mfma_f32_16x16x32_bf16(afrag[1], bfrag[1][ft], acc, 0, 0, 0);
        #pragma unroll
        for (int r = 0; r < 4; ++r) {
            int row = kq * 4 + r;               // C/D: col=lane&15, row=(lane>>4)*4+r
            int node = gr0 + row;
            if (node < n)
                hs2b[(size_t)node * HDIM + ft * 16 + col] = f2b(acc[r] * dinvs[nb0 + row]);
        }
    }
}

// ------- gather layer-2 (bf16 rows, 128 B) + fused mean partial --------------
#define ADD8(acc, v) do { \
    acc[0] += bl((v).x); acc[1] += bh((v).x); \
    acc[2] += bl((v).y); acc[3] += bh((v).y); \
    acc[4] += bl((v).z); acc[5] += bh((v).z); \
    acc[6] += bl((v).w); acc[7] += bh((v).w); } while (0)

__global__ __launch_bounds__(256) void gather2_kernel(const int* __restrict__ rowptr,
                                                      const int* __restrict__ csr,
                                                      const u16* __restrict__ hs2b,
                                                      const float* __restrict__ dinv,
                                                      const float* __restrict__ b2,
                                                      float* __restrict__ gpart, int n) {
    __shared__ float shp[4][64];
    int tid = threadIdx.x;
    int wv = tid >> 6;
    int lane = tid & 63;
    int rg = lane >> 3;        // 0..7
    int ch = lane & 7;         // 8-feature chunk (16 B)
    float b2c[8];
    #pragma unroll
    for (int j = 0; j < 8; ++j) b2c[j] = b2[ch * 8 + j];
    float vsum[8] = {0.f, 0.f, 0.f, 0.f, 0.f, 0.f, 0.f, 0.f};
    int gw = blockIdx.x * 4 + wv;
    for (int w = gw; w < n; w += GB2 * 4) {
        float acc[8] = {0.f, 0.f, 0.f, 0.f, 0.f, 0.f, 0.f, 0.f};
        if (rg == 0) {
            uint4 v = *reinterpret_cast<const uint4*>(hs2b + (size_t)w * HDIM + ch * 8);
            ADD8(acc, v);
        }
        int beg = rowptr[w], end = rowptr[w + 1];
        for (int base = beg; base < end; base += 64) {
            int cnt = min(64, end - base);
            int myi = (lane < cnt) ? csr[base + lane] : 0;
            int k = 0;
            for (; k + 16 <= cnt; k += 16) {
                int nb0 = __shfl(myi, k + rg);
                int nb1 = __shfl(myi, k + 8 + rg);
                uint4 v0 = *reinterpret_cast<const uint4*>(hs2b + (size_t)nb0 * HDIM + ch * 8);
                uint4 v1 = *reinterpret_cast<const uint4*>(hs2b + (size_t)nb1 * HDIM + ch * 8);
                ADD8(acc, v0);
                ADD8(acc, v1);
            }
            for (; k < cnt; k += 8) {
                int kk = k + rg;
                if (kk < cnt) {
                    int nb = __shfl(myi, kk);
                    uint4 v = *reinterpret_cast<const uint4*>(hs2b + (size_t)nb * HDIM + ch * 8);
                    ADD8(acc, v);
                }
            }
        }
        #pragma unroll
        for (int j = 0; j < 8; ++j) {
            acc[j] += __shfl_xor(acc[j], 8);
            acc[j] += __shfl_xor(acc[j], 16);
            acc[j] += __shfl_xor(acc[j], 32);
        }
        float dw = dinv[w];
        #pragma unroll
        for (int j = 0; j < 8; ++j)
            vsum[j] += fmaxf(acc[j] * dw + b2c[j], 0.0f);
    }
    if (rg == 0) {
        #pragma unroll
        for (int j = 0; j < 8; ++j) shp[wv][ch * 8 + j] = vsum[j];
    }
    __syncthreads();
    if (tid < 64)
        gpart[(size_t)blockIdx.x * HDIM + tid] =
            shp[0][tid] + shp[1][tid] + shp[2][tid] + shp[3][tid];
}

// ---- stage-2 parallel reduce: gpart[GB2][64] -> gpart2[GB2R][64] ------------
__global__ __launch_bounds__(256) void reduce2_kernel(const float* __restrict__ gpart,
                                                      float* __restrict__ gpart2) {
    __shared__ float lds[256];
    int tid = threadIdx.x;
    int q = tid >> 6;
    int f = tid & 63;
    const int rows = GB2 / GB2R;   // 32 rows per block
    int r0 = blockIdx.x * rows;
    float s = 0.0f;
    for (int r = r0 + q; r < r0 + rows; r += 4)
        s += gpart[(size_t)r * HDIM + f];
    lds[tid] = s;
    __syncthreads();
    if (tid < 64)
        gpart2[(size_t)blockIdx.x * HDIM + tid] =
            lds[tid] + lds[64 + tid] + lds[128 + tid] + lds[192 + tid];
}

// ---------------- final reduce + tiny MLP head --------------------------------
__global__ __launch_bounds__(256) void head_kernel(const float* __restrict__ gpart2,
                                                   const float* __restrict__ fcW1,
                                                   const float* __restrict__ fcb1,
                                                   const float* __restrict__ fcW2,
                                                   const float* __restrict__ fcb2,
                                                   float* __restrict__ out, int n) {
    __shared__ float lds[256];
    __shared__ float g[HDIM];
    __shared__ float t1[HDIM];
    int tid = threadIdx.x;
    int q = tid >> 6;
    int f = tid & 63;
    float s = 0.0f;
    for (int b = q; b < GB2R; b += 4) s += gpart2[(size_t)b * HDIM + f];
    lds[tid] = s;
    __syncthreads();
    if (tid < 64)
        g[tid] = (lds[tid] + lds[64 + tid] + lds[128 + tid] + lds[192 + tid]) *
                 (1.0f / (float)n);
    __syncthreads();
    if (tid < 64) {
        float acc = fcb1[tid];
        #pragma unroll
        for (int k = 0; k < HDIM; ++k) acc += g[k] * fcW1[k * HDIM + tid];
        t1[tid] = fmaxf(acc, 0.0f);
    }
    __syncthreads();
    if (tid < OUTDIM) {
        float acc = fcb2[tid];
        #pragma unroll
        for (int j = 0; j < HDIM; ++j) acc += t1[j] * fcW2[j * OUTDIM + tid];
        out[tid] = 1.0f / (1.0f + expf(-acc));
    }
}

extern "C" void kernel_launch(void* const* d_in, const int* in_sizes, int n_in,
                              void* d_out, int out_size, void* d_ws, size_t ws_size,
                              hipStream_t stream) {
    const float* x    = (const float*)d_in[0];
    const int*   ei   = (const int*)d_in[1];
    const float* W1   = (const float*)d_in[2];
    const float* b1   = (const float*)d_in[3];
    const float* W2   = (const float*)d_in[4];
    const float* b2   = (const float*)d_in[5];
    const float* fcW1 = (const float*)d_in[6];
    const float* fcb1 = (const float*)d_in[7];
    const float* fcW2 = (const float*)d_in[8];
    const float* fcb2 = (const float*)d_in[9];
    float* out = (float*)d_out;

    const int n = N_NODES;
    const int E = in_sizes[1] / 2;
    const int* src = ei;
    const int* dst = ei + E;

    char* ws = (char*)d_ws;
    size_t off = 0;
    auto alloc = [&](size_t bytes) -> void* {
        void* p = ws + off;
        off = (off + bytes + 255) & ~(size_t)255;
        return p;
    };
    float* dinv    = (float*)alloc((size_t)n * 4);
    int*   rowptr  = (int*)  alloc((size_t)(n + 1) * 4);
    int*   bCount  = (int*)  alloc((size_t)NB * CPAD * 4);
    int*   bBase   = (int*)  alloc((NB + 1) * 4);
    int*   bCursor = (int*)  alloc((size_t)NB * CPAD * 4);
    int*   csr     = (int*)  alloc((size_t)E * 4);
    int*   ebuf    = (int*)  alloc((size_t)E * 4);
    u16*   hs2b    = (u16*)  alloc((size_t)n * HDIM * 2);
    u16*   xsb     = (u16*)  alloc((size_t)n * INDIM * 2);
    float* aggx    = (float*)alloc((size_t)n * INDIM * 4);
    float* gpart   = (float*)alloc((size_t)GB2 * HDIM * 4);
    float* gpart2  = (float*)alloc((size_t)GB2R * HDIM * 4);
    (void)ws_size;

    hipMemsetAsync(bCount, 0, (size_t)NB * CPAD * 4, stream);

    // CSR build: hist -> scan -> partition -> per-bucket build (+rowptr +dinv)
    hist_kernel<<<512, 256, 0, stream>>>(dst, bCount, E);
    bscan_kernel<<<1, 256, 0, stream>>>(bCount, bBase, bCursor, rowptr, E);
    part_kernel<<<(E + CHUNK - 1) / CHUNK, 256, 0, stream>>>(src, dst, bCursor, ebuf, E);
    build_kernel<<<NB, 256, 0, stream>>>(ebuf, bBase, rowptr, csr, dinv, n);

    xs_kernel<<<(n * INDIM + 255) / 256, 256, 0, stream>>>(x, dinv, xsb, n * INDIM);

    int g1blocks = (n * 64 + 255) / 256;
    gather1_kernel<<<g1blocks, 256, 0, stream>>>(rowptr, csr, xsb, dinv, aggx, n);
    mm12_kernel<<<(n + 63) / 64, 256, 0, stream>>>(aggx, W1, b1, W2, dinv, hs2b, n);
    gather2_kernel<<<GB2, 256, 0, stream>>>(rowptr, csr, hs2b, dinv, b2, gpart, n);

    reduce2_kernel<<<GB2R, 256, 0, stream>>>(gpart, gpart2);
    head_kernel<<<1, 256, 0, stream>>>(gpart2, fcW1, fcb1, fcW2, fcb2, out, n);
}

// Round 13
// 293.843 us; speedup vs baseline: 2.3993x; 1.0732x over previous
//
#include <hip/hip_runtime.h>
#include <math.h>

#define N_NODES 100000
#define HDIM 64
#define INDIM 20
#define OUTDIM 128
#define GB2 2048    // gather2 grid blocks (4 waves each)
#define GB2R 64     // stage-2 reduction blocks
#define BSHIFT 9    // 512 nodes per bucket
#define NB 196      // ceil(100000 / 512)
#define CAP 18432   // edge capacity per bucket (mean 16384, +16 sigma)
#define CHUNK 3072  // edges per partition block
#define EPT 12      // edges per thread in part (CHUNK/256)
#define CPAD 16     // ints per padded counter (one 64B line)

typedef unsigned int  u32;
typedef unsigned short u16;
typedef unsigned char u8;
typedef __attribute__((ext_vector_type(8))) short short8;
typedef __attribute__((ext_vector_type(4))) float f32x4;

__device__ __forceinline__ float4 f4add(float4 a, float4 b) {
    return make_float4(a.x + b.x, a.y + b.y, a.z + b.z, a.w + b.w);
}
__device__ __forceinline__ float bl(u32 u) {   // low bf16 -> f32
    return __uint_as_float(u << 16);
}
__device__ __forceinline__ float bh(u32 u) {   // high bf16 -> f32
    return __uint_as_float(u & 0xffff0000u);
}
__device__ __forceinline__ u16 f2b(float f) {  // f32 -> bf16 (RNE)
    u32 u = __float_as_uint(f);
    return (u16)((u + 0x7fffu + ((u >> 16) & 1u)) >> 16);
}

// ---- partition edges into fixed-capacity bucket-grouped packed ebuf ---------
// packed = (src << 9) | (dst & 511). Edges carried in registers; chunk staged
// in LDS grouped by bucket; bucket runs written to global COALESCED.
// Bucket b owns ebuf[b*CAP .. b*CAP+count[b]); no histogram pre-pass needed.
__global__ __launch_bounds__(256) void part_kernel(const int* __restrict__ src,
                                                   const int* __restrict__ dst,
                                                   int* __restrict__ bucketCursor,
                                                   int* __restrict__ ebuf, int E) {
    __shared__ int cnt[NB];
    __shared__ int lofs[NB];
    __shared__ int gbase[NB];
    __shared__ int ps[256];
    __shared__ int stage[CHUNK];
    __shared__ u8  sbid[CHUNK];
    int tid = threadIdx.x;
    int e0 = blockIdx.x * CHUNK;
    int e1 = min(E, e0 + CHUNK);
    for (int b = tid; b < NB; b += 256) cnt[b] = 0;
    __syncthreads();
    int myb[EPT];
    int myp[EPT];
    #pragma unroll
    for (int j = 0; j < EPT; ++j) {
        int e = e0 + j * 256 + tid;
        if (e < e1) {
            int d = dst[e];
            int b = d >> BSHIFT;
            myb[j] = b;
            myp[j] = (src[e] << BSHIFT) | (d & ((1 << BSHIFT) - 1));
            atomicAdd(&cnt[b], 1);
        } else myb[j] = -1;
    }
    __syncthreads();
    int c = (tid < NB) ? cnt[tid] : 0;
    ps[tid] = c;
    __syncthreads();
    for (int off = 1; off < 256; off <<= 1) {
        int t = (tid >= off) ? ps[tid - off] : 0;
        __syncthreads();
        ps[tid] += t;
        __syncthreads();
    }
    if (tid < NB) {
        lofs[tid] = ps[tid] - c;                                  // local exclusive
        gbase[tid] = tid * CAP + (c ? atomicAdd(&bucketCursor[tid * CPAD], c) : 0);
        cnt[tid] = 0;                                             // reuse as cursor
    }
    __syncthreads();
    #pragma unroll
    for (int j = 0; j < EPT; ++j) {
        int b = myb[j];
        if (b >= 0) {
            int off = atomicAdd(&cnt[b], 1);
            int p = lofs[b] + off;
            stage[p] = myp[j];
            sbid[p] = (u8)b;
        }
    }
    __syncthreads();
    int total = e1 - e0;
    for (int i = tid; i < total; i += 256) {
        int b = sbid[i];
        ebuf[gbase[b] + (i - lofs[b])] = stage[i];                // coalesced per run
    }
}

// ---- per-bucket CSR build + rowbeg/deg/dinv (all LDS atomics) ---------------
__global__ __launch_bounds__(256) void build_kernel(const int* __restrict__ ebuf,
                                                    const int* __restrict__ bucketCursor,
                                                    int* __restrict__ rowbeg,
                                                    u16* __restrict__ degv,
                                                    int* __restrict__ csr,
                                                    float* __restrict__ dinv, int n) {
    __shared__ int hist[512];
    __shared__ int cur[512];
    __shared__ int ps[256];
    int tid = threadIdx.x;
    int b = blockIdx.x;
    int nodeBase = b << BSHIFT;
    int ebeg = b * CAP;
    int eend = ebeg + bucketCursor[b * CPAD];
    hist[tid] = 0; hist[tid + 256] = 0;
    cur[tid] = 0;  cur[tid + 256] = 0;
    __syncthreads();
    for (int e = ebeg + tid; e < eend; e += 256)
        atomicAdd(&hist[ebuf[e] & 511], 1);
    __syncthreads();
    int s0 = hist[2 * tid], s1 = hist[2 * tid + 1];
    ps[tid] = s0 + s1;
    __syncthreads();
    for (int off = 1; off < 256; off <<= 1) {
        int t = (tid >= off) ? ps[tid - off] : 0;
        __syncthreads();
        ps[tid] += t;
        __syncthreads();
    }
    int ex = ps[tid] - (s0 + s1);   // exclusive prefix for node 2*tid
    int i0 = 2 * tid, i1 = 2 * tid + 1;
    if (nodeBase + i0 < n) {
        rowbeg[nodeBase + i0] = ebeg + ex;
        degv[nodeBase + i0] = (u16)s0;
        dinv[nodeBase + i0] = rsqrtf((float)s0 + 1.0f);
    }
    if (nodeBase + i1 < n) {
        rowbeg[nodeBase + i1] = ebeg + ex + s0;
        degv[nodeBase + i1] = (u16)s1;
        dinv[nodeBase + i1] = rsqrtf((float)s1 + 1.0f);
    }
    hist[i0] = ex;
    hist[i1] = ex + s0;
    __syncthreads();
    for (int e = ebeg + tid; e < eend; e += 256) {
        int p = ebuf[e];
        int d = p & 511;
        int pos = hist[d] + atomicAdd(&cur[d], 1);
        csr[ebeg + pos] = p >> BSHIFT;   // p >= 0, logical shift
    }
}

// ---- xs = bf16(x * dinv) ----------------------------------------------------
__global__ __launch_bounds__(256) void xs_kernel(const float* __restrict__ x,
                                                 const float* __restrict__ dinv,
                                                 u16* __restrict__ xsb, int total) {
    int g = blockIdx.x * 256 + threadIdx.x;
    if (g < total) xsb[g] = f2b(x[g] * dinv[g / INDIM]);
}

// ------- gather layer-1 in INPUT space (bf16 rows, 40 B) ---------------------
__global__ __launch_bounds__(256) void gather1_kernel(const int* __restrict__ rowbeg,
                                                      const u16* __restrict__ degv,
                                                      const int* __restrict__ csr,
                                                      const u16* __restrict__ xsb,
                                                      const float* __restrict__ dinv,
                                                      float* __restrict__ aggx, int n) {
    int tid = threadIdx.x;
    int w = (blockIdx.x * 256 + tid) >> 6;
    int lane = tid & 63;
    if (w >= n) return;
    int rg = lane / 5;
    int ch = lane - rg * 5;     // 4-feature chunk (8 B)
    bool act = lane < 60;
    float4 acc = make_float4(0.f, 0.f, 0.f, 0.f);
    if (rg == 0) {
        uint2 u = *reinterpret_cast<const uint2*>(xsb + (size_t)w * INDIM + ch * 4);
        acc = make_float4(bl(u.x), bh(u.x), bl(u.y), bh(u.y));
    }
    int beg = rowbeg[w];
    int end = beg + degv[w];
    for (int base = beg; base < end; base += 64) {
        int cnt = min(64, end - base);
        int myi = (lane < cnt) ? csr[base + lane] : 0;
        int k = 0;
        for (; k + 12 <= cnt; k += 12) {
            int nb = __shfl(myi, k + rg);
            if (act) {
                uint2 u = *reinterpret_cast<const uint2*>(xsb + (size_t)nb * INDIM + ch * 4);
                acc = f4add(acc, make_float4(bl(u.x), bh(u.x), bl(u.y), bh(u.y)));
            }
        }
        if (k < cnt) {
            int kk = k + rg;
            if (act && kk < cnt) {
                int nb = __shfl(myi, kk);
                uint2 u = *reinterpret_cast<const uint2*>(xsb + (size_t)nb * INDIM + ch * 4);
                acc = f4add(acc, make_float4(bl(u.x), bh(u.x), bl(u.y), bh(u.y)));
            }
        }
    }
    #define F4DOWN(v, d) make_float4(__shfl_down((v).x, d), __shfl_down((v).y, d), \
                                     __shfl_down((v).z, d), __shfl_down((v).w, d))
    acc = f4add(acc, F4DOWN(acc, 30));
    acc = f4add(acc, F4DOWN(acc, 15));
    float4 a5 = F4DOWN(acc, 5);
    float4 a10 = F4DOWN(acc, 10);
    acc = f4add(f4add(acc, a5), a10);
    if (lane < 5) {
        float dw = dinv[w];
        float4 o = make_float4(acc.x * dw, acc.y * dw, acc.z * dw, acc.w * dw);
        *reinterpret_cast<float4*>(&aggx[(size_t)w * INDIM + lane * 4]) = o;
    }
}

// ------- fused mm: v1 = relu(aggx@W1+b1) [VALU]; hs2b = bf16((v1@W2)*dinv) [MFMA]
__global__ __launch_bounds__(256) void mm12_kernel(const float* __restrict__ aggx,
                                                   const float* __restrict__ W1,
                                                   const float* __restrict__ b1,
                                                   const float* __restrict__ W2,
                                                   const float* __restrict__ dinv,
                                                   u16* __restrict__ hs2b, int n) {
    __shared__ float W1s[INDIM * HDIM];   // 5 KB
    __shared__ float ax[4][INDIM];
    __shared__ u16 v1b[64][72];           // 64 nodes x 64 k bf16, pad to 72
    __shared__ float dinvs[64];
    int tid = threadIdx.x;
    for (int idx = tid; idx < INDIM * HDIM; idx += 256) W1s[idx] = W1[idx];
    int i00 = blockIdx.x * 64;
    if (tid < 64) dinvs[tid] = (i00 + tid < n) ? dinv[i00 + tid] : 0.0f;

    int lane = tid & 63;
    int col = lane & 15, kq = lane >> 4;
    short8 bfrag[2][4];
    #pragma unroll
    for (int kh = 0; kh < 2; ++kh)
        #pragma unroll
        for (int ft = 0; ft < 4; ++ft)
            #pragma unroll
            for (int i = 0; i < 8; ++i) {
                int k = kh * 32 + kq * 8 + i;
                bfrag[kh][ft][i] = (short)f2b(W2[k * HDIM + ft * 16 + col]);
            }

    int sub = tid >> 6, f = tid & 63;
    for (int p = 0; p < 16; ++p) {
        int i0 = i00 + p * 4;
        __syncthreads();
        for (int idx = tid; idx < 4 * INDIM; idx += 256) {
            int node = i0 + idx / INDIM;
            ax[idx / INDIM][idx % INDIM] =
                (node < n) ? aggx[(size_t)node * INDIM + idx % INDIM] : 0.0f;
        }
        __syncthreads();
        float acc = b1[f];
        #pragma unroll
        for (int k = 0; k < INDIM; ++k) acc += ax[sub][k] * W1s[k * HDIM + f];
        v1b[p * 4 + sub][f] = f2b(fmaxf(acc, 0.0f));
    }
    __syncthreads();

    int wv = tid >> 6;
    int nb0 = wv * 16;
    short8 afrag[2];
    #pragma unroll
    for (int kh = 0; kh < 2; ++kh) {
        const u16* ap = &v1b[nb0 + col][kh * 32 + kq * 8];
        afrag[kh] = *reinterpret_cast<const short8*>(ap);
    }
    int gr0 = i00 + nb0;
    #pragma unroll
    for (int ft = 0; ft < 4; ++ft) {
        f32x4 acc = {0.f, 0.f, 0.f, 0.f};
        acc = __builtin_amdgcn_mfma_f32_16x16x32_bf16(afrag[0], bfrag[0][ft], acc, 0, 0, 0);
        acc = __builtin_amdgcn_mfma_f32_16x16x32_bf16(afrag[1], bfrag[1][ft], acc, 0, 0, 0);
        #pragma unroll
        for (int r = 0; r < 4; ++r) {
            int row = kq * 4 + r;               // C/D: col=lane&15, row=(lane>>4)*4+r
            int node = gr0 + row;
            if (node < n)
                hs2b[(size_t)node * HDIM + ft * 16 + col] = f2b(acc[r] * dinvs[nb0 + row]);
        }
    }
}

// ------- gather layer-2 (bf16 rows, 128 B) + fused mean partial --------------
#define ADD8(acc, v) do { \
    acc[0] += bl((v).x); acc[1] += bh((v).x); \
    acc[2] += bl((v).y); acc[3] += bh((v).y); \
    acc[4] += bl((v).z); acc[5] += bh((v).z); \
    acc[6] += bl((v).w); acc[7] += bh((v).w); } while (0)

__global__ __launch_bounds__(256) void gather2_kernel(const int* __restrict__ rowbeg,
                                                      const u16* __restrict__ degv,
                                                      const int* __restrict__ csr,
                                                      const u16* __restrict__ hs2b,
                                                      const float* __restrict__ dinv,
                                                      const float* __restrict__ b2,
                                                      float* __restrict__ gpart, int n) {
    __shared__ float shp[4][64];
    int tid = threadIdx.x;
    int wv = tid >> 6;
    int lane = tid & 63;
    int rg = lane >> 3;        // 0..7
    int ch = lane & 7;         // 8-feature chunk (16 B)
    float b2c[8];
    #pragma unroll
    for (int j = 0; j < 8; ++j) b2c[j] = b2[ch * 8 + j];
    float vsum[8] = {0.f, 0.f, 0.f, 0.f, 0.f, 0.f, 0.f, 0.f};
    int gw = blockIdx.x * 4 + wv;
    for (int w = gw; w < n; w += GB2 * 4) {
        float acc[8] = {0.f, 0.f, 0.f, 0.f, 0.f, 0.f, 0.f, 0.f};
        if (rg == 0) {
            uint4 v = *reinterpret_cast<const uint4*>(hs2b + (size_t)w * HDIM + ch * 8);
            ADD8(acc, v);
        }
        int beg = rowbeg[w];
        int end = beg + degv[w];
        for (int base = beg; base < end; base += 64) {
            int cnt = min(64, end - base);
            int myi = (lane < cnt) ? csr[base + lane] : 0;
            int k = 0;
            for (; k + 16 <= cnt; k += 16) {
                int nb0 = __shfl(myi, k + rg);
                int nb1 = __shfl(myi, k + 8 + rg);
                uint4 v0 = *reinterpret_cast<const uint4*>(hs2b + (size_t)nb0 * HDIM + ch * 8);
                uint4 v1 = *reinterpret_cast<const uint4*>(hs2b + (size_t)nb1 * HDIM + ch * 8);
                ADD8(acc, v0);
                ADD8(acc, v1);
            }
            for (; k < cnt; k += 8) {
                int kk = k + rg;
                if (kk < cnt) {
                    int nb = __shfl(myi, kk);
                    uint4 v = *reinterpret_cast<const uint4*>(hs2b + (size_t)nb * HDIM + ch * 8);
                    ADD8(acc, v);
                }
            }
        }
        #pragma unroll
        for (int j = 0; j < 8; ++j) {
            acc[j] += __shfl_xor(acc[j], 8);
            acc[j] += __shfl_xor(acc[j], 16);
            acc[j] += __shfl_xor(acc[j], 32);
        }
        float dw = dinv[w];
        #pragma unroll
        for (int j = 0; j < 8; ++j)
            vsum[j] += fmaxf(acc[j] * dw + b2c[j], 0.0f);
    }
    if (rg == 0) {
        #pragma unroll
        for (int j = 0; j < 8; ++j) shp[wv][ch * 8 + j] = vsum[j];
    }
    __syncthreads();
    if (tid < 64)
        gpart[(size_t)blockIdx.x * HDIM + tid] =
            shp[0][tid] + shp[1][tid] + shp[2][tid] + shp[3][tid];
}

// ---- stage-2 parallel reduce: gpart[GB2][64] -> gpart2[GB2R][64] ------------
__global__ __launch_bounds__(256) void reduce2_kernel(const float* __restrict__ gpart,
                                                      float* __restrict__ gpart2) {
    __shared__ float lds[256];
    int tid = threadIdx.x;
    int q = tid >> 6;
    int f = tid & 63;
    const int rows = GB2 / GB2R;   // 32 rows per block
    int r0 = blockIdx.x * rows;
    float s = 0.0f;
    for (int r = r0 + q; r < r0 + rows; r += 4)
        s += gpart[(size_t)r * HDIM + f];
    lds[tid] = s;
    __syncthreads();
    if (tid < 64)
        gpart2[(size_t)blockIdx.x * HDIM + tid] =
            lds[tid] + lds[64 + tid] + lds[128 + tid] + lds[192 + tid];
}

// ---------------- final reduce + tiny MLP head --------------------------------
__global__ __launch_bounds__(256) void head_kernel(const float* __restrict__ gpart2,
                                                   const float* __restrict__ fcW1,
                                                   const float* __restrict__ fcb1,
                                                   const float* __restrict__ fcW2,
                                                   const float* __restrict__ fcb2,
                                                   float* __restrict__ out, int n) {
    __shared__ float lds[256];
    __shared__ float g[HDIM];
    __shared__ float t1[HDIM];
    int tid = threadIdx.x;
    int q = tid >> 6;
    int f = tid & 63;
    float s = 0.0f;
    for (int b = q; b < GB2R; b += 4) s += gpart2[(size_t)b * HDIM + f];
    lds[tid] = s;
    __syncthreads();
    if (tid < 64)
        g[tid] = (lds[tid] + lds[64 + tid] + lds[128 + tid] + lds[192 + tid]) *
                 (1.0f / (float)n);
    __syncthreads();
    if (tid < 64) {
        float acc = fcb1[tid];
        #pragma unroll
        for (int k = 0; k < HDIM; ++k) acc += g[k] * fcW1[k * HDIM + tid];
        t1[tid] = fmaxf(acc, 0.0f);
    }
    __syncthreads();
    if (tid < OUTDIM) {
        float acc = fcb2[tid];
        #pragma unroll
        for (int j = 0; j < HDIM; ++j) acc += t1[j] * fcW2[j * OUTDIM + tid];
        out[tid] = 1.0f / (1.0f + expf(-acc));
    }
}

extern "C" void kernel_launch(void* const* d_in, const int* in_sizes, int n_in,
                              void* d_out, int out_size, void* d_ws, size_t ws_size,
                              hipStream_t stream) {
    const float* x    = (const float*)d_in[0];
    const int*   ei   = (const int*)d_in[1];
    const float* W1   = (const float*)d_in[2];
    const float* b1   = (const float*)d_in[3];
    const float* W2   = (const float*)d_in[4];
    const float* b2   = (const float*)d_in[5];
    const float* fcW1 = (const float*)d_in[6];
    const float* fcb1 = (const float*)d_in[7];
    const float* fcW2 = (const float*)d_in[8];
    const float* fcb2 = (const float*)d_in[9];
    float* out = (float*)d_out;

    const int n = N_NODES;
    const int E = in_sizes[1] / 2;
    const int* src = ei;
    const int* dst = ei + E;

    char* ws = (char*)d_ws;
    size_t off = 0;
    auto alloc = [&](size_t bytes) -> void* {
        void* p = ws + off;
        off = (off + bytes + 255) & ~(size_t)255;
        return p;
    };
    float* dinv    = (float*)alloc((size_t)n * 4);
    int*   rowbeg  = (int*)  alloc((size_t)n * 4);
    u16*   degv    = (u16*)  alloc((size_t)n * 2);
    int*   bCursor = (int*)  alloc((size_t)NB * CPAD * 4);
    int*   csr     = (int*)  alloc((size_t)NB * CAP * 4);
    int*   ebuf    = (int*)  alloc((size_t)NB * CAP * 4);
    u16*   hs2b    = (u16*)  alloc((size_t)n * HDIM * 2);
    u16*   xsb     = (u16*)  alloc((size_t)n * INDIM * 2);
    float* aggx    = (float*)alloc((size_t)n * INDIM * 4);
    float* gpart   = (float*)alloc((size_t)GB2 * HDIM * 4);
    float* gpart2  = (float*)alloc((size_t)GB2R * HDIM * 4);
    (void)ws_size;

    hipMemsetAsync(bCursor, 0, (size_t)NB * CPAD * 4, stream);

    // CSR build: partition (fixed-capacity buckets) -> per-bucket build
    part_kernel<<<(E + CHUNK - 1) / CHUNK, 256, 0, stream>>>(src, dst, bCursor, ebuf, E);
    build_kernel<<<NB, 256, 0, stream>>>(ebuf, bCursor, rowbeg, degv, csr, dinv, n);

    xs_kernel<<<(n * INDIM + 255) / 256, 256, 0, stream>>>(x, dinv, xsb, n * INDIM);

    int g1blocks = (n * 64 + 255) / 256;
    gather1_kernel<<<g1blocks, 256, 0, stream>>>(rowbeg, degv, csr, xsb, dinv, aggx, n);
    mm12_kernel<<<(n + 63) / 64, 256, 0, stream>>>(aggx, W1, b1, W2, dinv, hs2b, n);
    gather2_kernel<<<GB2, 256, 0, stream>>>(rowbeg, degv, csr, hs2b, dinv, b2, gpart, n);

    reduce2_kernel<<<GB2R, 256, 0, stream>>>(gpart, gpart2);
    head_kernel<<<1, 256, 0, stream>>>(gpart2, fcW1, fcb1, fcW2, fcb2, out, n);
}